// Round 1
// baseline (345.525 us; speedup 1.0000x reference)
//
#include <hip/hip_runtime.h>
#include <math.h>

// Qwen3 MoE sparse block, MI355X/gfx950.
// Sizes fixed by the reference: T=2048 tokens, H=1024, E=16, I=512, top-4.
constexpr int TT = 2048;   // tokens
constexpr int HH = 1024;   // hidden
constexpr int EE = 16;     // experts
constexpr int II = 512;    // intermediate

typedef unsigned short u16;
typedef short s16x8 __attribute__((ext_vector_type(8)));   // 8 bf16 for MFMA A/B
typedef float f32x4 __attribute__((ext_vector_type(4)));   // MFMA C/D

__device__ __forceinline__ u16 f2bf(float f) {
  unsigned u = __float_as_uint(f);
  u = (u + 0x7fffu + ((u >> 16) & 1u)) >> 16;   // round-to-nearest-even
  return (u16)u;
}

// async global->LDS, 16B per lane; lds base must be wave-uniform (HW adds lane*16)
__device__ __forceinline__ void gl2lds16(const void* g, void* l) {
  __builtin_amdgcn_global_load_lds(
      (const __attribute__((address_space(1))) unsigned*)g,
      (__attribute__((address_space(3))) unsigned*)l, 16, 0, 0);
}

// ---------------- cast x (fp32 -> bf16) ----------------
__global__ void cast_x_kernel(const float* __restrict__ x, u16* __restrict__ xb) {
  int i = blockIdx.x * blockDim.x + threadIdx.x;   // grid covers T*H/4 exactly
  float4 v = reinterpret_cast<const float4*>(x)[i];
  ushort4 o;
  o.x = f2bf(v.x); o.y = f2bf(v.y); o.z = f2bf(v.z); o.w = f2bf(v.w);
  reinterpret_cast<ushort4*>(xb)[i] = o;
}

// ---------- transpose+cast weights: [K][N] fp32 -> [N][K] bf16 ----------
__global__ void wtrans_kernel(const float* __restrict__ wgp, const float* __restrict__ wup,
                              const float* __restrict__ wdp, u16* __restrict__ wgt,
                              u16* __restrict__ wut, u16* __restrict__ wdt) {
  int z = blockIdx.z;
  int e = z & 15, t = z >> 4;
  const float* src; u16* dst; int K, N;
  if (t == 0)      { src = wgp + (size_t)e * HH * II; dst = wgt + (size_t)e * II * HH; K = HH; N = II; }
  else if (t == 1) { src = wup + (size_t)e * HH * II; dst = wut + (size_t)e * II * HH; K = HH; N = II; }
  else             { src = wdp + (size_t)e * II * HH; dst = wdt + (size_t)e * HH * II; K = II; N = HH; }
  int bx = blockIdx.x, by = blockIdx.y;
  if (bx * 32 >= N || by * 32 >= K) return;
  __shared__ float tile[32][33];
  int tx = threadIdx.x & 31, ty = threadIdx.x >> 5;   // 32x8
  int col = bx * 32 + tx;
#pragma unroll
  for (int j = 0; j < 4; ++j) {
    int row = by * 32 + ty + j * 8;
    tile[ty + j * 8][tx] = src[(size_t)row * N + col];
  }
  __syncthreads();
#pragma unroll
  for (int j = 0; j < 4; ++j) {
    int orow = bx * 32 + ty + j * 8;
    dst[(size_t)orow * K + by * 32 + tx] = f2bf(tile[tx][ty + j * 8]);
  }
}

// ---------------- router: logits, top-4, scatter to per-expert lists ----------------
__global__ void router_kernel(const float* __restrict__ x, const float* __restrict__ wg,
                              float* __restrict__ rl, int* __restrict__ counts,
                              int* __restrict__ tlist, float* __restrict__ wlist) {
  int lane = threadIdx.x & 63, wv = threadIdx.x >> 6;
  int t = blockIdx.x * 4 + wv;          // one wave per token
  const float* xr = x + (size_t)t * HH;
  float xv[16];
#pragma unroll
  for (int i = 0; i < 16; ++i) xv[i] = xr[lane + 64 * i];
  float lg[16];
#pragma unroll
  for (int e = 0; e < 16; ++e) {
    float p = 0.f;
#pragma unroll
    for (int i = 0; i < 16; ++i) p += xv[i] * wg[(lane + 64 * i) * 16 + e];
#pragma unroll
    for (int s = 32; s > 0; s >>= 1) p += __shfl_xor(p, s, 64);
    lg[e] = p;   // all lanes hold the full logit after butterfly
  }
  // top-4 (stable: earlier index wins ties, matches lax.top_k)
  unsigned mask = 0;
  int sel[4]; float bl[4];
#pragma unroll
  for (int k = 0; k < 4; ++k) {
    float best = -3.4e38f; int bi = 0;
#pragma unroll
    for (int e = 0; e < 16; ++e) {
      bool ok = !((mask >> e) & 1u) && (lg[e] > best);
      best = ok ? lg[e] : best;
      bi = ok ? e : bi;
    }
    mask |= 1u << bi;
    sel[k] = bi; bl[k] = best;
  }
  // normalized top-k softmax: full denominator cancels
  float mx = bl[0];
  float wk[4]; float s = 0.f;
#pragma unroll
  for (int k = 0; k < 4; ++k) { wk[k] = expf(bl[k] - mx); s += wk[k]; }
  float inv = 1.f / s;
  if (lane == 0) {
#pragma unroll
    for (int e = 0; e < 16; ++e) rl[(size_t)t * 16 + e] = lg[e];
#pragma unroll
    for (int k = 0; k < 4; ++k) {
      int e = sel[k];
      int pos = atomicAdd(&counts[e], 1);
      tlist[e * TT + pos] = t;
      wlist[e * TT + pos] = wk[k] * inv;
    }
  }
}

__global__ void scan_kernel(const int* __restrict__ counts, int* __restrict__ offsets) {
  if (threadIdx.x == 0) {
    int s = 0;
    for (int e = 0; e < 16; ++e) { offsets[e] = s; s += counts[e]; }
    offsets[16] = s;
  }
}

// ---------------- gate+up fused GEMM -> hidden (bf16, pre-scaled by routing weight) ----------------
// Tile 128x128, BK=64, 4 waves 2x2, each wave 64x64 (4x4 frags of 16x16x32 bf16 MFMA).
__global__ __launch_bounds__(256, 2) void gateup_kernel(
    const u16* __restrict__ xb, const u16* __restrict__ wgt, const u16* __restrict__ wut,
    const int* __restrict__ counts, const int* __restrict__ offsets,
    const int* __restrict__ tlist, const float* __restrict__ wlist,
    u16* __restrict__ hidden) {
  int e = blockIdx.z, mt = blockIdx.y, nt = blockIdx.x;
  int cnt = counts[e];
  if (mt * 128 >= cnt) return;
  __shared__ u16 As[128 * 64];   // [m][k]
  __shared__ u16 Bg[128 * 64];   // [n][k]
  __shared__ u16 Bu[128 * 64];
  int tid = threadIdx.x, lane = tid & 63, wv = tid >> 6;
  int wm = wv >> 1, wn = wv & 1;
  int srow = lane >> 3;            // staging: 8 lanes/row, 16B each
  int scol = (lane & 7) * 8;       // bf16 elements
  const u16* wgE = wgt + (size_t)e * II * HH;
  const u16* wuE = wut + (size_t)e * II * HH;
  const u16* gA[4]; const u16* gBg[4]; const u16* gBu[4];
#pragma unroll
  for (int c = 0; c < 4; ++c) {
    int chunk = c * 4 + wv;                 // 16 chunks of 8 rows per tile
    int m = chunk * 8 + srow;
    int mi = mt * 128 + m; if (mi >= cnt) mi = cnt - 1;   // clamp pad rows
    int tok = tlist[e * TT + mi];           // row gather via per-lane global addr
    gA[c]  = xb  + (size_t)tok * HH + scol;
    int n = nt * 128 + chunk * 8 + srow;
    gBg[c] = wgE + (size_t)n * HH + scol;
    gBu[c] = wuE + (size_t)n * HH + scol;
  }
  f32x4 accG[4][4] = {}; f32x4 accU[4][4] = {};
  for (int k0 = 0; k0 < HH; k0 += 64) {
#pragma unroll
    for (int c = 0; c < 4; ++c) {
      int chunk = c * 4 + wv;
      gl2lds16(gA[c]  + k0, &As[chunk * 512]);
      gl2lds16(gBg[c] + k0, &Bg[chunk * 512]);
      gl2lds16(gBu[c] + k0, &Bu[chunk * 512]);
    }
    __syncthreads();
#pragma unroll
    for (int kk = 0; kk < 64; kk += 32) {
      s16x8 a[4], bg[4], bu[4];
      int koff = kk + (lane >> 4) * 8;
#pragma unroll
      for (int f = 0; f < 4; ++f) {
        a[f]  = *reinterpret_cast<const s16x8*>(&As[(wm * 64 + f * 16 + (lane & 15)) * 64 + koff]);
        bg[f] = *reinterpret_cast<const s16x8*>(&Bg[(wn * 64 + f * 16 + (lane & 15)) * 64 + koff]);
        bu[f] = *reinterpret_cast<const s16x8*>(&Bu[(wn * 64 + f * 16 + (lane & 15)) * 64 + koff]);
      }
#pragma unroll
      for (int fm = 0; fm < 4; ++fm)
#pragma unroll
        for (int fn = 0; fn < 4; ++fn) {
          accG[fm][fn] = __builtin_amdgcn_mfma_f32_16x16x32_bf16(a[fm], bg[fn], accG[fm][fn], 0, 0, 0);
          accU[fm][fn] = __builtin_amdgcn_mfma_f32_16x16x32_bf16(a[fm], bu[fn], accU[fm][fn], 0, 0, 0);
        }
    }
    __syncthreads();
  }
  // epilogue: hidden = w_route * silu(g) * u   (C/D: col=lane&15, row=quad*4+reg)
  int hb = offsets[e];
  int quad = lane >> 4, colc = lane & 15;
#pragma unroll
  for (int fm = 0; fm < 4; ++fm) {
#pragma unroll
    for (int r = 0; r < 4; ++r) {
      int mi = mt * 128 + wm * 64 + fm * 16 + quad * 4 + r;
      if (mi < cnt) {
        float wr = wlist[e * TT + mi];
        u16* hrow = hidden + (size_t)(hb + mi) * II + nt * 128 + wn * 64;
#pragma unroll
        for (int fn = 0; fn < 4; ++fn) {
          float g = accG[fm][fn][r], u = accU[fm][fn][r];
          float hval = wr * u * g / (1.f + expf(-g));
          hrow[fn * 16 + colc] = f2bf(hval);
        }
      }
    }
  }
}

// ---------------- down GEMM: hidden @ wd^T -> atomicAdd into out ----------------
__global__ __launch_bounds__(256, 2) void down_kernel(
    const u16* __restrict__ hidden, const u16* __restrict__ wdt,
    const int* __restrict__ counts, const int* __restrict__ offsets,
    const int* __restrict__ tlist, float* __restrict__ out) {
  int e = blockIdx.z, mt = blockIdx.y, nt = blockIdx.x;
  int cnt = counts[e];
  if (mt * 128 >= cnt) return;
  int hb = offsets[e];
  __shared__ u16 As[128 * 64];
  __shared__ u16 Bs[128 * 64];
  int tid = threadIdx.x, lane = tid & 63, wv = tid >> 6;
  int wm = wv >> 1, wn = wv & 1;
  int srow = lane >> 3, scol = (lane & 7) * 8;
  const u16* wdE = wdt + (size_t)e * HH * II;
  const u16* gA[4]; const u16* gB[4];
#pragma unroll
  for (int c = 0; c < 4; ++c) {
    int chunk = c * 4 + wv;
    int row = hb + mt * 128 + chunk * 8 + srow;
    if (row > EE * TT / 4 * 4 - 1) row = EE * TT / 4 * 4 - 1;   // clamp to 8191
    if (row > 8191) row = 8191;
    gA[c] = hidden + (size_t)row * II + scol;
    int n = nt * 128 + chunk * 8 + srow;
    gB[c] = wdE + (size_t)n * II + scol;
  }
  f32x4 acc[4][4] = {};
  for (int k0 = 0; k0 < II; k0 += 64) {
#pragma unroll
    for (int c = 0; c < 4; ++c) {
      int chunk = c * 4 + wv;
      gl2lds16(gA[c] + k0, &As[chunk * 512]);
      gl2lds16(gB[c] + k0, &Bs[chunk * 512]);
    }
    __syncthreads();
#pragma unroll
    for (int kk = 0; kk < 64; kk += 32) {
      s16x8 a[4], b[4];
      int koff = kk + (lane >> 4) * 8;
#pragma unroll
      for (int f = 0; f < 4; ++f) {
        a[f] = *reinterpret_cast<const s16x8*>(&As[(wm * 64 + f * 16 + (lane & 15)) * 64 + koff]);
        b[f] = *reinterpret_cast<const s16x8*>(&Bs[(wn * 64 + f * 16 + (lane & 15)) * 64 + koff]);
      }
#pragma unroll
      for (int fm = 0; fm < 4; ++fm)
#pragma unroll
        for (int fn = 0; fn < 4; ++fn)
          acc[fm][fn] = __builtin_amdgcn_mfma_f32_16x16x32_bf16(a[fm], b[fn], acc[fm][fn], 0, 0, 0);
    }
    __syncthreads();
  }
  int quad = lane >> 4, colc = lane & 15;
#pragma unroll
  for (int fm = 0; fm < 4; ++fm) {
#pragma unroll
    for (int r = 0; r < 4; ++r) {
      int mi = mt * 128 + wm * 64 + fm * 16 + quad * 4 + r;
      if (mi < cnt) {
        int tok = tlist[e * TT + mi];
        float* orow = out + (size_t)tok * HH + nt * 128 + wn * 64;
#pragma unroll
        for (int fn = 0; fn < 4; ++fn)
          atomicAdd(&orow[fn * 16 + colc], acc[fm][fn][r]);
      }
    }
  }
}

extern "C" void kernel_launch(void* const* d_in, const int* in_sizes, int n_in,
                              void* d_out, int out_size, void* d_ws, size_t ws_size,
                              hipStream_t stream) {
  const float* x   = (const float*)d_in[0];   // [1,2048,1024]
  const float* wg  = (const float*)d_in[1];   // [1024,16]
  const float* wgp = (const float*)d_in[2];   // [16,1024,512]
  const float* wup = (const float*)d_in[3];   // [16,1024,512]
  const float* wdp = (const float*)d_in[4];   // [16,512,1024]
  float* out = (float*)d_out;                 // [2048*1024] then router_logits [2048*16]
  float* rl  = out + (size_t)TT * HH;

  char* w = (char*)d_ws;
  int*   counts  = (int*)(w + 0);                        // 16 ints
  int*   offsets = (int*)(w + 64);                       // 17 ints
  int*   tlist   = (int*)(w + 1024);                     // [E][T] token ids
  float* wlist   = (float*)(w + 1024 + 131072);          // [E][T] routing weights
  u16*   xb      = (u16*)(w + 263168);                   // [T][H] bf16
  u16*   wgt     = xb  + (size_t)TT * HH;                // [E][I][H] bf16 (transposed)
  u16*   wut     = wgt + (size_t)EE * II * HH;
  u16*   wdt     = wut + (size_t)EE * II * HH;           // [E][H][I] bf16 (transposed)
  u16*   hidden  = wdt + (size_t)EE * HH * II;           // [8192][I] bf16

  hipMemsetAsync(counts, 0, 64, stream);
  hipMemsetAsync(out, 0, (size_t)TT * HH * sizeof(float), stream);

  hipLaunchKernelGGL(cast_x_kernel, dim3(TT * HH / 1024), dim3(256), 0, stream, x, xb);
  hipLaunchKernelGGL(wtrans_kernel, dim3(32, 32, 48), dim3(256), 0, stream,
                     wgp, wup, wdp, wgt, wut, wdt);
  hipLaunchKernelGGL(router_kernel, dim3(TT / 4), dim3(256), 0, stream,
                     x, wg, rl, counts, tlist, wlist);
  hipLaunchKernelGGL(scan_kernel, dim3(1), dim3(64), 0, stream, counts, offsets);
  hipLaunchKernelGGL(gateup_kernel, dim3(4, 16, 16), dim3(256), 0, stream,
                     xb, wgt, wut, counts, offsets, tlist, wlist, hidden);
  hipLaunchKernelGGL(down_kernel, dim3(8, 16, 16), dim3(256), 0, stream,
                     hidden, wdt, counts, offsets, tlist, out);
}

// Round 2
// 344.527 us; speedup vs baseline: 1.0029x; 1.0029x over previous
//
#include <hip/hip_runtime.h>
#include <math.h>

// Qwen3 MoE sparse block, MI355X/gfx950.
// Sizes fixed by the reference: T=2048 tokens, H=1024, E=16, I=512, top-4.
constexpr int TT = 2048;   // tokens
constexpr int HH = 1024;   // hidden
constexpr int EE = 16;     // experts
constexpr int II = 512;    // intermediate

typedef unsigned short u16;
typedef short s16x8 __attribute__((ext_vector_type(8)));   // 8 bf16 for MFMA A/B
typedef float f32x4 __attribute__((ext_vector_type(4)));   // MFMA C/D

__device__ __forceinline__ u16 f2bf(float f) {
  unsigned u = __float_as_uint(f);
  u = (u + 0x7fffu + ((u >> 16) & 1u)) >> 16;   // round-to-nearest-even
  return (u16)u;
}

// async global->LDS, 16B per lane; lds base must be wave-uniform (HW adds lane*16)
__device__ __forceinline__ void gl2lds16(const void* g, void* l) {
  __builtin_amdgcn_global_load_lds(
      (const __attribute__((address_space(1))) unsigned*)g,
      (__attribute__((address_space(3))) unsigned*)l, 16, 0, 0);
}

// ---------------- cast x (fp32 -> bf16) + transpose wg -> wgT [E][H] fp32 ----------------
__global__ void cast_x_kernel(const float* __restrict__ x, u16* __restrict__ xb,
                              const float* __restrict__ wg, float* __restrict__ wgT) {
  int b = blockIdx.x;
  if (b < TT * HH / 1024) {
    int i = b * blockDim.x + threadIdx.x;
    float4 v = reinterpret_cast<const float4*>(x)[i];
    ushort4 o;
    o.x = f2bf(v.x); o.y = f2bf(v.y); o.z = f2bf(v.z); o.w = f2bf(v.w);
    reinterpret_cast<ushort4*>(xb)[i] = o;
  } else {
    // 64 blocks x 256 threads cover 16384 = H*E entries
    int i = (b - TT * HH / 1024) * blockDim.x + threadIdx.x;
    int h = i >> 4, e = i & 15;
    wgT[e * HH + h] = wg[i];   // read coalesced; write 16 streams (64 KB total, one-shot)
  }
}

// ---------- transpose+cast weights: [K][N] fp32 -> [N][K] bf16 ----------
__global__ void wtrans_kernel(const float* __restrict__ wgp, const float* __restrict__ wup,
                              const float* __restrict__ wdp, u16* __restrict__ wgt,
                              u16* __restrict__ wut, u16* __restrict__ wdt) {
  int z = blockIdx.z;
  int e = z & 15, t = z >> 4;
  const float* src; u16* dst; int K, N;
  if (t == 0)      { src = wgp + (size_t)e * HH * II; dst = wgt + (size_t)e * II * HH; K = HH; N = II; }
  else if (t == 1) { src = wup + (size_t)e * HH * II; dst = wut + (size_t)e * II * HH; K = HH; N = II; }
  else             { src = wdp + (size_t)e * II * HH; dst = wdt + (size_t)e * HH * II; K = II; N = HH; }
  int bx = blockIdx.x, by = blockIdx.y;
  if (bx * 32 >= N || by * 32 >= K) return;
  __shared__ float tile[32][33];
  int tx = threadIdx.x & 31, ty = threadIdx.x >> 5;   // 32x8
  int col = bx * 32 + tx;
#pragma unroll
  for (int j = 0; j < 4; ++j) {
    int row = by * 32 + ty + j * 8;
    tile[ty + j * 8][tx] = src[(size_t)row * N + col];
  }
  __syncthreads();
#pragma unroll
  for (int j = 0; j < 4; ++j) {
    int orow = bx * 32 + ty + j * 8;
    dst[(size_t)orow * K + by * 32 + tx] = f2bf(tile[tx][ty + j * 8]);
  }
}

// ---------------- router: logits, top-4, scatter to per-expert lists ----------------
// Uses pre-transposed wgT [E][H] so every load is coalesced.
__global__ void router_kernel(const float* __restrict__ x, const float* __restrict__ wgT,
                              float* __restrict__ rl, int* __restrict__ counts,
                              int* __restrict__ tlist, float* __restrict__ wlist) {
  int lane = threadIdx.x & 63, wv = threadIdx.x >> 6;
  int t = blockIdx.x * 4 + wv;          // one wave per token
  const float* xr = x + (size_t)t * HH;
  float xv[16];
#pragma unroll
  for (int i = 0; i < 16; ++i) xv[i] = xr[lane + 64 * i];
  float lg[16];
#pragma unroll
  for (int e = 0; e < 16; ++e) {
    const float* wr = wgT + (size_t)e * HH;
    float p = 0.f;
#pragma unroll
    for (int i = 0; i < 16; ++i) p += xv[i] * wr[lane + 64 * i];
#pragma unroll
    for (int s = 32; s > 0; s >>= 1) p += __shfl_xor(p, s, 64);
    lg[e] = p;   // all lanes hold the full logit after butterfly
  }
  if (lane < 16) rl[(size_t)t * 16 + lane] = lg[lane];
  // top-4 (stable: earlier index wins ties, matches lax.top_k)
  unsigned mask = 0;
  int sel[4]; float bl[4];
#pragma unroll
  for (int k = 0; k < 4; ++k) {
    float best = -3.4e38f; int bi = 0;
#pragma unroll
    for (int e = 0; e < 16; ++e) {
      bool ok = !((mask >> e) & 1u) && (lg[e] > best);
      best = ok ? lg[e] : best;
      bi = ok ? e : bi;
    }
    mask |= 1u << bi;
    sel[k] = bi; bl[k] = best;
  }
  // normalized top-k softmax: full denominator cancels
  float mx = bl[0];
  float wk[4]; float s = 0.f;
#pragma unroll
  for (int k = 0; k < 4; ++k) { wk[k] = expf(bl[k] - mx); s += wk[k]; }
  float inv = 1.f / s;
  if (lane == 0) {
#pragma unroll
    for (int k = 0; k < 4; ++k) {
      int e = sel[k];
      int pos = atomicAdd(&counts[e], 1);
      tlist[e * TT + pos] = t;
      wlist[e * TT + pos] = wk[k] * inv;
    }
  }
}

__global__ void scan_kernel(const int* __restrict__ counts, int* __restrict__ offsets) {
  if (threadIdx.x == 0) {
    int s = 0;
    for (int e = 0; e < 16; ++e) { offsets[e] = s; s += counts[e]; }
    offsets[16] = s;
  }
}

// ---------------- gate+up fused GEMM -> hidden (bf16, pre-scaled by routing weight) ----------------
// Tile 128x128, BK=64, 4 waves 2x2, each wave 64x64 (4x4 frags of 16x16x32 bf16 MFMA).
__global__ __launch_bounds__(256, 2) void gateup_kernel(
    const u16* __restrict__ xb, const u16* __restrict__ wgt, const u16* __restrict__ wut,
    const int* __restrict__ counts, const int* __restrict__ offsets,
    const int* __restrict__ tlist, const float* __restrict__ wlist,
    u16* __restrict__ hidden) {
  int e = blockIdx.z, mt = blockIdx.y, nt = blockIdx.x;
  int cnt = counts[e];
  if (mt * 128 >= cnt) return;
  __shared__ u16 As[128 * 64];   // [m][k]
  __shared__ u16 Bg[128 * 64];   // [n][k]
  __shared__ u16 Bu[128 * 64];
  int tid = threadIdx.x, lane = tid & 63, wv = tid >> 6;
  int wm = wv >> 1, wn = wv & 1;
  int srow = lane >> 3;            // staging: 8 lanes/row, 16B each
  int scol = (lane & 7) * 8;       // bf16 elements
  const u16* wgE = wgt + (size_t)e * II * HH;
  const u16* wuE = wut + (size_t)e * II * HH;
  const u16* gA[4]; const u16* gBg[4]; const u16* gBu[4];
#pragma unroll
  for (int c = 0; c < 4; ++c) {
    int chunk = c * 4 + wv;                 // 16 chunks of 8 rows per tile
    int m = chunk * 8 + srow;
    int mi = mt * 128 + m; if (mi >= cnt) mi = cnt - 1;   // clamp pad rows
    int tok = tlist[e * TT + mi];           // row gather via per-lane global addr
    gA[c]  = xb  + (size_t)tok * HH + scol;
    int n = nt * 128 + chunk * 8 + srow;
    gBg[c] = wgE + (size_t)n * HH + scol;
    gBu[c] = wuE + (size_t)n * HH + scol;
  }
  f32x4 accG[4][4] = {}; f32x4 accU[4][4] = {};
  for (int k0 = 0; k0 < HH; k0 += 64) {
#pragma unroll
    for (int c = 0; c < 4; ++c) {
      int chunk = c * 4 + wv;
      gl2lds16(gA[c]  + k0, &As[chunk * 512]);
      gl2lds16(gBg[c] + k0, &Bg[chunk * 512]);
      gl2lds16(gBu[c] + k0, &Bu[chunk * 512]);
    }
    __syncthreads();
#pragma unroll
    for (int kk = 0; kk < 64; kk += 32) {
      s16x8 a[4], bg[4], bu[4];
      int koff = kk + (lane >> 4) * 8;
#pragma unroll
      for (int f = 0; f < 4; ++f) {
        a[f]  = *reinterpret_cast<const s16x8*>(&As[(wm * 64 + f * 16 + (lane & 15)) * 64 + koff]);
        bg[f] = *reinterpret_cast<const s16x8*>(&Bg[(wn * 64 + f * 16 + (lane & 15)) * 64 + koff]);
        bu[f] = *reinterpret_cast<const s16x8*>(&Bu[(wn * 64 + f * 16 + (lane & 15)) * 64 + koff]);
      }
#pragma unroll
      for (int fm = 0; fm < 4; ++fm)
#pragma unroll
        for (int fn = 0; fn < 4; ++fn) {
          accG[fm][fn] = __builtin_amdgcn_mfma_f32_16x16x32_bf16(a[fm], bg[fn], accG[fm][fn], 0, 0, 0);
          accU[fm][fn] = __builtin_amdgcn_mfma_f32_16x16x32_bf16(a[fm], bu[fn], accU[fm][fn], 0, 0, 0);
        }
    }
    __syncthreads();
  }
  // epilogue: hidden = w_route * silu(g) * u   (C/D: col=lane&15, row=quad*4+reg)
  int hb = offsets[e];
  int quad = lane >> 4, colc = lane & 15;
#pragma unroll
  for (int fm = 0; fm < 4; ++fm) {
#pragma unroll
    for (int r = 0; r < 4; ++r) {
      int mi = mt * 128 + wm * 64 + fm * 16 + quad * 4 + r;
      if (mi < cnt) {
        float wr = wlist[e * TT + mi];
        u16* hrow = hidden + (size_t)(hb + mi) * II + nt * 128 + wn * 64;
#pragma unroll
        for (int fn = 0; fn < 4; ++fn) {
          float g = accG[fm][fn][r], u = accU[fm][fn][r];
          float hval = wr * u * g / (1.f + expf(-g));
          hrow[fn * 16 + colc] = f2bf(hval);
        }
      }
    }
  }
}

// ---------------- down GEMM: hidden @ wd^T -> atomicAdd into out ----------------
__global__ __launch_bounds__(256, 2) void down_kernel(
    const u16* __restrict__ hidden, const u16* __restrict__ wdt,
    const int* __restrict__ counts, const int* __restrict__ offsets,
    const int* __restrict__ tlist, float* __restrict__ out) {
  int e = blockIdx.z, mt = blockIdx.y, nt = blockIdx.x;
  int cnt = counts[e];
  if (mt * 128 >= cnt) return;
  int hb = offsets[e];
  __shared__ u16 As[128 * 64];
  __shared__ u16 Bs[128 * 64];
  int tid = threadIdx.x, lane = tid & 63, wv = tid >> 6;
  int wm = wv >> 1, wn = wv & 1;
  int srow = lane >> 3, scol = (lane & 7) * 8;
  const u16* wdE = wdt + (size_t)e * HH * II;
  const u16* gA[4]; const u16* gB[4];
#pragma unroll
  for (int c = 0; c < 4; ++c) {
    int chunk = c * 4 + wv;
    int row = hb + mt * 128 + chunk * 8 + srow;
    if (row > 8191) row = 8191;   // clamp pad rows into the hidden buffer
    gA[c] = hidden + (size_t)row * II + scol;
    int n = nt * 128 + chunk * 8 + srow;
    gB[c] = wdE + (size_t)n * II + scol;
  }
  f32x4 acc[4][4] = {};
  for (int k0 = 0; k0 < II; k0 += 64) {
#pragma unroll
    for (int c = 0; c < 4; ++c) {
      int chunk = c * 4 + wv;
      gl2lds16(gA[c] + k0, &As[chunk * 512]);
      gl2lds16(gB[c] + k0, &Bs[chunk * 512]);
    }
    __syncthreads();
#pragma unroll
    for (int kk = 0; kk < 64; kk += 32) {
      s16x8 a[4], b[4];
      int koff = kk + (lane >> 4) * 8;
#pragma unroll
      for (int f = 0; f < 4; ++f) {
        a[f] = *reinterpret_cast<const s16x8*>(&As[(wm * 64 + f * 16 + (lane & 15)) * 64 + koff]);
        b[f] = *reinterpret_cast<const s16x8*>(&Bs[(wn * 64 + f * 16 + (lane & 15)) * 64 + koff]);
      }
#pragma unroll
      for (int fm = 0; fm < 4; ++fm)
#pragma unroll
        for (int fn = 0; fn < 4; ++fn)
          acc[fm][fn] = __builtin_amdgcn_mfma_f32_16x16x32_bf16(a[fm], b[fn], acc[fm][fn], 0, 0, 0);
    }
    __syncthreads();
  }
  int quad = lane >> 4, colc = lane & 15;
#pragma unroll
  for (int fm = 0; fm < 4; ++fm) {
#pragma unroll
    for (int r = 0; r < 4; ++r) {
      int mi = mt * 128 + wm * 64 + fm * 16 + quad * 4 + r;
      if (mi < cnt) {
        int tok = tlist[e * TT + mi];
        float* orow = out + (size_t)tok * HH + nt * 128 + wn * 64;
#pragma unroll
        for (int fn = 0; fn < 4; ++fn)
          atomicAdd(&orow[fn * 16 + colc], acc[fm][fn][r]);
      }
    }
  }
}

extern "C" void kernel_launch(void* const* d_in, const int* in_sizes, int n_in,
                              void* d_out, int out_size, void* d_ws, size_t ws_size,
                              hipStream_t stream) {
  const float* x   = (const float*)d_in[0];   // [1,2048,1024]
  const float* wg  = (const float*)d_in[1];   // [1024,16]
  const float* wgp = (const float*)d_in[2];   // [16,1024,512]
  const float* wup = (const float*)d_in[3];   // [16,1024,512]
  const float* wdp = (const float*)d_in[4];   // [16,512,1024]
  float* out = (float*)d_out;                 // [2048*1024] then router_logits [2048*16]
  float* rl  = out + (size_t)TT * HH;

  char* w = (char*)d_ws;
  int*   counts  = (int*)(w + 0);                        // 16 ints
  int*   offsets = (int*)(w + 64);                       // 17 ints
  int*   tlist   = (int*)(w + 1024);                     // [E][T] token ids
  float* wlist   = (float*)(w + 1024 + 131072);          // [E][T] routing weights
  float* wgT     = (float*)(w + 1024 + 262144);          // [E][H] fp32 transposed router weights
  u16*   xb      = (u16*)(w + 1024 + 262144 + 65536 + 1024);   // [T][H] bf16
  u16*   wgt     = xb  + (size_t)TT * HH;                // [E][I][H] bf16 (transposed)
  u16*   wut     = wgt + (size_t)EE * II * HH;
  u16*   wdt     = wut + (size_t)EE * II * HH;           // [E][H][I] bf16 (transposed)
  u16*   hidden  = wdt + (size_t)EE * HH * II;           // [8192][I] bf16

  hipMemsetAsync(counts, 0, 64, stream);
  hipMemsetAsync(out, 0, (size_t)TT * HH * sizeof(float), stream);

  hipLaunchKernelGGL(cast_x_kernel, dim3(TT * HH / 1024 + 64), dim3(256), 0, stream,
                     x, xb, wg, wgT);
  hipLaunchKernelGGL(wtrans_kernel, dim3(32, 32, 48), dim3(256), 0, stream,
                     wgp, wup, wdp, wgt, wut, wdt);
  hipLaunchKernelGGL(router_kernel, dim3(TT / 4), dim3(256), 0, stream,
                     x, wgT, rl, counts, tlist, wlist);
  hipLaunchKernelGGL(scan_kernel, dim3(1), dim3(64), 0, stream, counts, offsets);
  hipLaunchKernelGGL(gateup_kernel, dim3(4, 16, 16), dim3(256), 0, stream,
                     xb, wgt, wut, counts, offsets, tlist, wlist, hidden);
  hipLaunchKernelGGL(down_kernel, dim3(8, 16, 16), dim3(256), 0, stream,
                     hidden, wdt, counts, offsets, tlist, out);
}

// Round 3
// 272.397 us; speedup vs baseline: 1.2685x; 1.2648x over previous
//
#include <hip/hip_runtime.h>
#include <math.h>

// Qwen3 MoE sparse block, MI355X/gfx950.
// Sizes fixed by the reference: T=2048 tokens, H=1024, E=16, I=512, top-4.
constexpr int TT = 2048;   // tokens
constexpr int HH = 1024;   // hidden
constexpr int EE = 16;     // experts
constexpr int II = 512;    // intermediate

typedef unsigned short u16;
typedef short s16x8 __attribute__((ext_vector_type(8)));   // 8 bf16 for MFMA A/B
typedef float f32x4 __attribute__((ext_vector_type(4)));   // MFMA C/D

__device__ __forceinline__ u16 f2bf(float f) {
  unsigned u = __float_as_uint(f);
  u = (u + 0x7fffu + ((u >> 16) & 1u)) >> 16;   // round-to-nearest-even
  return (u16)u;
}

// async global->LDS, 16B per lane; lds base must be wave-uniform (HW adds lane*16)
__device__ __forceinline__ void gl2lds16(const void* g, void* l) {
  __builtin_amdgcn_global_load_lds(
      (const __attribute__((address_space(1))) unsigned*)g,
      (__attribute__((address_space(3))) unsigned*)l, 16, 0, 0);
}

// ---------------- cast x (fp32 -> bf16) + transpose wg -> wgT [E][H] fp32 ----------------
__global__ void cast_x_kernel(const float* __restrict__ x, u16* __restrict__ xb,
                              const float* __restrict__ wg, float* __restrict__ wgT) {
  int b = blockIdx.x;
  if (b < TT * HH / 1024) {
    int i = b * blockDim.x + threadIdx.x;
    float4 v = reinterpret_cast<const float4*>(x)[i];
    ushort4 o;
    o.x = f2bf(v.x); o.y = f2bf(v.y); o.z = f2bf(v.z); o.w = f2bf(v.w);
    reinterpret_cast<ushort4*>(xb)[i] = o;
  } else {
    // 64 blocks x 256 threads cover 16384 = H*E entries
    int i = (b - TT * HH / 1024) * blockDim.x + threadIdx.x;
    int h = i >> 4, e = i & 15;
    wgT[e * HH + h] = wg[i];   // read coalesced; write 16 streams (64 KB total, one-shot)
  }
}

// ---------- transpose+cast weights: [K][N] fp32 -> [N][K] bf16 ----------
__global__ void wtrans_kernel(const float* __restrict__ wgp, const float* __restrict__ wup,
                              const float* __restrict__ wdp, u16* __restrict__ wgt,
                              u16* __restrict__ wut, u16* __restrict__ wdt) {
  int z = blockIdx.z;
  int e = z & 15, t = z >> 4;
  const float* src; u16* dst; int K, N;
  if (t == 0)      { src = wgp + (size_t)e * HH * II; dst = wgt + (size_t)e * II * HH; K = HH; N = II; }
  else if (t == 1) { src = wup + (size_t)e * HH * II; dst = wut + (size_t)e * II * HH; K = HH; N = II; }
  else             { src = wdp + (size_t)e * II * HH; dst = wdt + (size_t)e * HH * II; K = II; N = HH; }
  int bx = blockIdx.x, by = blockIdx.y;
  if (bx * 32 >= N || by * 32 >= K) return;
  __shared__ float tile[32][33];
  int tx = threadIdx.x & 31, ty = threadIdx.x >> 5;   // 32x8
  int col = bx * 32 + tx;
#pragma unroll
  for (int j = 0; j < 4; ++j) {
    int row = by * 32 + ty + j * 8;
    tile[ty + j * 8][tx] = src[(size_t)row * N + col];
  }
  __syncthreads();
#pragma unroll
  for (int j = 0; j < 4; ++j) {
    int orow = bx * 32 + ty + j * 8;
    dst[(size_t)orow * K + by * 32 + tx] = f2bf(tile[tx][ty + j * 8]);
  }
}

// ---------------- router: logits, top-4, per-token sel/weights. NO atomics. ----------------
// (R1 post-mortem: 8192 returning atomicAdds to one 64B line serialized at ~30cyc each = 105us.)
__global__ void router_kernel(const float* __restrict__ x, const float* __restrict__ wgT,
                              float* __restrict__ rl, unsigned* __restrict__ selmask,
                              float* __restrict__ wsel) {
  int lane = threadIdx.x & 63, wv = threadIdx.x >> 6;
  int t = blockIdx.x * 4 + wv;          // one wave per token
  const float* xr = x + (size_t)t * HH;
  float xv[16];
#pragma unroll
  for (int i = 0; i < 16; ++i) xv[i] = xr[lane + 64 * i];
  float lg[16];
#pragma unroll
  for (int e = 0; e < 16; ++e) {
    const float* wr = wgT + (size_t)e * HH;
    float p = 0.f;
#pragma unroll
    for (int i = 0; i < 16; ++i) p += xv[i] * wr[lane + 64 * i];
#pragma unroll
    for (int s = 32; s > 0; s >>= 1) p += __shfl_xor(p, s, 64);
    lg[e] = p;   // all lanes hold the full logit after butterfly
  }
  if (lane < 16) rl[(size_t)t * 16 + lane] = lg[lane];
  // top-4 (stable: earlier index wins ties, matches lax.top_k)
  unsigned mask = 0;
  int sel[4]; float bl[4];
#pragma unroll
  for (int k = 0; k < 4; ++k) {
    float best = -3.4e38f; int bi = 0;
#pragma unroll
    for (int e = 0; e < 16; ++e) {
      bool ok = !((mask >> e) & 1u) && (lg[e] > best);
      best = ok ? lg[e] : best;
      bi = ok ? e : bi;
    }
    mask |= 1u << bi;
    sel[k] = bi; bl[k] = best;
  }
  // normalized top-k softmax: full denominator cancels
  float mx = bl[0];
  float wk[4]; float s = 0.f;
#pragma unroll
  for (int k = 0; k < 4; ++k) { wk[k] = expf(bl[k] - mx); s += wk[k]; }
  float inv = 1.f / s;
  if (lane == 0) {
    selmask[t] = (unsigned)sel[0] | ((unsigned)sel[1] << 4) |
                 ((unsigned)sel[2] << 8) | ((unsigned)sel[3] << 12);
    float4 w4 = make_float4(wk[0] * inv, wk[1] * inv, wk[2] * inv, wk[3] * inv);
    reinterpret_cast<float4*>(wsel)[t] = w4;
  }
}

// ---------------- build per-expert lists: 1 block, 16 waves, ballot-compaction ----------------
// Deterministic, token-sorted, zero global atomics. Also computes counts+offsets.
__global__ void build_lists_kernel(const unsigned* __restrict__ selmask,
                                   const float* __restrict__ wsel,
                                   int* __restrict__ counts, int* __restrict__ offsets,
                                   int* __restrict__ tlist, float* __restrict__ wlist) {
  __shared__ int scnt[16];
  int lane = threadIdx.x & 63, e = threadIdx.x >> 6;   // wave e handles expert e
  int base = 0;
  for (int t0 = 0; t0 < TT; t0 += 64) {
    int t = t0 + lane;
    unsigned m = selmask[t];
    int k = -1;
#pragma unroll
    for (int j = 0; j < 4; ++j)
      if (((m >> (4 * j)) & 15u) == (unsigned)e) k = j;
    unsigned long long bal = __ballot(k >= 0);
    int pos = base + (int)__popcll(bal & ((1ull << lane) - 1ull));
    if (k >= 0) {
      tlist[e * TT + pos] = t;
      wlist[e * TT + pos] = wsel[t * 4 + k];
    }
    base += (int)__popcll(bal);
  }
  if (lane == 0) scnt[e] = base;
  __syncthreads();
  if (threadIdx.x == 0) {
    int s = 0;
    for (int i = 0; i < 16; ++i) { counts[i] = scnt[i]; offsets[i] = s; s += scnt[i]; }
    offsets[16] = s;
  }
}

// ---------------- gate+up fused GEMM -> hidden (bf16, pre-scaled by routing weight) ----------------
// Tile 128x128, BK=64, 4 waves 2x2, each wave 64x64 (4x4 frags of 16x16x32 bf16 MFMA).
__global__ __launch_bounds__(256, 2) void gateup_kernel(
    const u16* __restrict__ xb, const u16* __restrict__ wgt, const u16* __restrict__ wut,
    const int* __restrict__ counts, const int* __restrict__ offsets,
    const int* __restrict__ tlist, const float* __restrict__ wlist,
    u16* __restrict__ hidden) {
  int e = blockIdx.z, mt = blockIdx.y, nt = blockIdx.x;
  int cnt = counts[e];
  if (mt * 128 >= cnt) return;
  __shared__ u16 As[128 * 64];   // [m][k]
  __shared__ u16 Bg[128 * 64];   // [n][k]
  __shared__ u16 Bu[128 * 64];
  int tid = threadIdx.x, lane = tid & 63, wv = tid >> 6;
  int wm = wv >> 1, wn = wv & 1;
  int srow = lane >> 3;            // staging: 8 lanes/row, 16B each
  int scol = (lane & 7) * 8;       // bf16 elements
  const u16* wgE = wgt + (size_t)e * II * HH;
  const u16* wuE = wut + (size_t)e * II * HH;
  const u16* gA[4]; const u16* gBg[4]; const u16* gBu[4];
#pragma unroll
  for (int c = 0; c < 4; ++c) {
    int chunk = c * 4 + wv;                 // 16 chunks of 8 rows per tile
    int m = chunk * 8 + srow;
    int mi = mt * 128 + m; if (mi >= cnt) mi = cnt - 1;   // clamp pad rows
    int tok = tlist[e * TT + mi];           // row gather via per-lane global addr
    gA[c]  = xb  + (size_t)tok * HH + scol;
    int n = nt * 128 + chunk * 8 + srow;
    gBg[c] = wgE + (size_t)n * HH + scol;
    gBu[c] = wuE + (size_t)n * HH + scol;
  }
  f32x4 accG[4][4] = {}; f32x4 accU[4][4] = {};
  for (int k0 = 0; k0 < HH; k0 += 64) {
#pragma unroll
    for (int c = 0; c < 4; ++c) {
      int chunk = c * 4 + wv;
      gl2lds16(gA[c]  + k0, &As[chunk * 512]);
      gl2lds16(gBg[c] + k0, &Bg[chunk * 512]);
      gl2lds16(gBu[c] + k0, &Bu[chunk * 512]);
    }
    __syncthreads();
#pragma unroll
    for (int kk = 0; kk < 64; kk += 32) {
      s16x8 a[4], bg[4], bu[4];
      int koff = kk + (lane >> 4) * 8;
#pragma unroll
      for (int f = 0; f < 4; ++f) {
        a[f]  = *reinterpret_cast<const s16x8*>(&As[(wm * 64 + f * 16 + (lane & 15)) * 64 + koff]);
        bg[f] = *reinterpret_cast<const s16x8*>(&Bg[(wn * 64 + f * 16 + (lane & 15)) * 64 + koff]);
        bu[f] = *reinterpret_cast<const s16x8*>(&Bu[(wn * 64 + f * 16 + (lane & 15)) * 64 + koff]);
      }
#pragma unroll
      for (int fm = 0; fm < 4; ++fm)
#pragma unroll
        for (int fn = 0; fn < 4; ++fn) {
          accG[fm][fn] = __builtin_amdgcn_mfma_f32_16x16x32_bf16(a[fm], bg[fn], accG[fm][fn], 0, 0, 0);
          accU[fm][fn] = __builtin_amdgcn_mfma_f32_16x16x32_bf16(a[fm], bu[fn], accU[fm][fn], 0, 0, 0);
        }
    }
    __syncthreads();
  }
  // epilogue: hidden = w_route * silu(g) * u   (C/D: col=lane&15, row=quad*4+reg)
  int hb = offsets[e];
  int quad = lane >> 4, colc = lane & 15;
#pragma unroll
  for (int fm = 0; fm < 4; ++fm) {
#pragma unroll
    for (int r = 0; r < 4; ++r) {
      int mi = mt * 128 + wm * 64 + fm * 16 + quad * 4 + r;
      if (mi < cnt) {
        float wr = wlist[e * TT + mi];
        u16* hrow = hidden + (size_t)(hb + mi) * II + nt * 128 + wn * 64;
#pragma unroll
        for (int fn = 0; fn < 4; ++fn) {
          float g = accG[fm][fn][r], u = accU[fm][fn][r];
          float hval = wr * u * g / (1.f + expf(-g));
          hrow[fn * 16 + colc] = f2bf(hval);
        }
      }
    }
  }
}

// ---------------- down GEMM: hidden @ wd^T -> atomicAdd into out ----------------
__global__ __launch_bounds__(256, 2) void down_kernel(
    const u16* __restrict__ hidden, const u16* __restrict__ wdt,
    const int* __restrict__ counts, const int* __restrict__ offsets,
    const int* __restrict__ tlist, float* __restrict__ out) {
  int e = blockIdx.z, mt = blockIdx.y, nt = blockIdx.x;
  int cnt = counts[e];
  if (mt * 128 >= cnt) return;
  int hb = offsets[e];
  __shared__ u16 As[128 * 64];
  __shared__ u16 Bs[128 * 64];
  int tid = threadIdx.x, lane = tid & 63, wv = tid >> 6;
  int wm = wv >> 1, wn = wv & 1;
  int srow = lane >> 3, scol = (lane & 7) * 8;
  const u16* wdE = wdt + (size_t)e * HH * II;
  const u16* gA[4]; const u16* gB[4];
#pragma unroll
  for (int c = 0; c < 4; ++c) {
    int chunk = c * 4 + wv;
    int row = hb + mt * 128 + chunk * 8 + srow;
    if (row > 8191) row = 8191;   // clamp pad rows into the hidden buffer
    gA[c] = hidden + (size_t)row * II + scol;
    int n = nt * 128 + chunk * 8 + srow;
    gB[c] = wdE + (size_t)n * II + scol;
  }
  f32x4 acc[4][4] = {};
  for (int k0 = 0; k0 < II; k0 += 64) {
#pragma unroll
    for (int c = 0; c < 4; ++c) {
      int chunk = c * 4 + wv;
      gl2lds16(gA[c] + k0, &As[chunk * 512]);
      gl2lds16(gB[c] + k0, &Bs[chunk * 512]);
    }
    __syncthreads();
#pragma unroll
    for (int kk = 0; kk < 64; kk += 32) {
      s16x8 a[4], b[4];
      int koff = kk + (lane >> 4) * 8;
#pragma unroll
      for (int f = 0; f < 4; ++f) {
        a[f] = *reinterpret_cast<const s16x8*>(&As[(wm * 64 + f * 16 + (lane & 15)) * 64 + koff]);
        b[f] = *reinterpret_cast<const s16x8*>(&Bs[(wn * 64 + f * 16 + (lane & 15)) * 64 + koff]);
      }
#pragma unroll
      for (int fm = 0; fm < 4; ++fm)
#pragma unroll
        for (int fn = 0; fn < 4; ++fn)
          acc[fm][fn] = __builtin_amdgcn_mfma_f32_16x16x32_bf16(a[fm], b[fn], acc[fm][fn], 0, 0, 0);
    }
    __syncthreads();
  }
  int quad = lane >> 4, colc = lane & 15;
#pragma unroll
  for (int fm = 0; fm < 4; ++fm) {
#pragma unroll
    for (int r = 0; r < 4; ++r) {
      int mi = mt * 128 + wm * 64 + fm * 16 + quad * 4 + r;
      if (mi < cnt) {
        int tok = tlist[e * TT + mi];
        float* orow = out + (size_t)tok * HH + nt * 128 + wn * 64;
#pragma unroll
        for (int fn = 0; fn < 4; ++fn)
          atomicAdd(&orow[fn * 16 + colc], acc[fm][fn][r]);
      }
    }
  }
}

extern "C" void kernel_launch(void* const* d_in, const int* in_sizes, int n_in,
                              void* d_out, int out_size, void* d_ws, size_t ws_size,
                              hipStream_t stream) {
  const float* x   = (const float*)d_in[0];   // [1,2048,1024]
  const float* wg  = (const float*)d_in[1];   // [1024,16]
  const float* wgp = (const float*)d_in[2];   // [16,1024,512]
  const float* wup = (const float*)d_in[3];   // [16,1024,512]
  const float* wdp = (const float*)d_in[4];   // [16,512,1024]
  float* out = (float*)d_out;                 // [2048*1024] then router_logits [2048*16]
  float* rl  = out + (size_t)TT * HH;

  char* w = (char*)d_ws;
  int*      counts  = (int*)(w + 0);                  // 16 ints
  int*      offsets = (int*)(w + 64);                 // 17 ints
  unsigned* selmask = (unsigned*)(w + 1024);          // [T] packed 4x4-bit expert ids
  float*    wsel    = (float*)(w + 1024 + 8192);      // [T][4] normalized weights
  int*      tlist   = (int*)(w + 49152);              // [E][T] token ids
  float*    wlist   = (float*)(w + 49152 + 131072);   // [E][T] routing weights
  float*    wgT     = (float*)(w + 49152 + 262144);   // [E][H] fp32 transposed router weights
  u16*      xb      = (u16*)(w + 49152 + 262144 + 65536);   // [T][H] bf16
  u16*      wgt     = xb  + (size_t)TT * HH;          // [E][I][H] bf16 (transposed)
  u16*      wut     = wgt + (size_t)EE * II * HH;
  u16*      wdt     = wut + (size_t)EE * II * HH;     // [E][H][I] bf16 (transposed)
  u16*      hidden  = wdt + (size_t)EE * HH * II;     // [8192][I] bf16

  hipMemsetAsync(out, 0, (size_t)TT * HH * sizeof(float), stream);

  hipLaunchKernelGGL(cast_x_kernel, dim3(TT * HH / 1024 + 64), dim3(256), 0, stream,
                     x, xb, wg, wgT);
  hipLaunchKernelGGL(wtrans_kernel, dim3(32, 32, 48), dim3(256), 0, stream,
                     wgp, wup, wdp, wgt, wut, wdt);
  hipLaunchKernelGGL(router_kernel, dim3(TT / 4), dim3(256), 0, stream,
                     x, wgT, rl, selmask, wsel);
  hipLaunchKernelGGL(build_lists_kernel, dim3(1), dim3(1024), 0, stream,
                     selmask, wsel, counts, offsets, tlist, wlist);
  hipLaunchKernelGGL(gateup_kernel, dim3(4, 16, 16), dim3(256), 0, stream,
                     xb, wgt, wut, counts, offsets, tlist, wlist, hidden);
  hipLaunchKernelGGL(down_kernel, dim3(8, 16, 16), dim3(256), 0, stream,
                     hidden, wdt, counts, offsets, tlist, out);
}

// Round 4
// 262.612 us; speedup vs baseline: 1.3157x; 1.0373x over previous
//
#include <hip/hip_runtime.h>
#include <math.h>

// Qwen3 MoE sparse block, MI355X/gfx950.
// Sizes fixed by the reference: T=2048 tokens, H=1024, E=16, I=512, top-4.
constexpr int TT = 2048;   // tokens
constexpr int HH = 1024;   // hidden
constexpr int EE = 16;     // experts
constexpr int II = 512;    // intermediate

typedef unsigned short u16;
typedef short s16x8 __attribute__((ext_vector_type(8)));   // 8 bf16 for MFMA A/B
typedef float f32x4 __attribute__((ext_vector_type(4)));   // MFMA C/D

__device__ __forceinline__ u16 f2bf(float f) {
  unsigned u = __float_as_uint(f);
  u = (u + 0x7fffu + ((u >> 16) & 1u)) >> 16;   // round-to-nearest-even
  return (u16)u;
}

// async global->LDS, 16B per lane; lds base must be wave-uniform (HW adds lane*16)
__device__ __forceinline__ void gl2lds16(const void* g, void* l) {
  __builtin_amdgcn_global_load_lds(
      (const __attribute__((address_space(1))) unsigned*)g,
      (__attribute__((address_space(3))) unsigned*)l, 16, 0, 0);
}

// ---------------- cast x (fp32 -> bf16) + transpose wg -> wgT [E][H] fp32 ----------------
__global__ void cast_x_kernel(const float* __restrict__ x, u16* __restrict__ xb,
                              const float* __restrict__ wg, float* __restrict__ wgT) {
  int b = blockIdx.x;
  if (b < TT * HH / 1024) {
    int i = b * blockDim.x + threadIdx.x;
    float4 v = reinterpret_cast<const float4*>(x)[i];
    ushort4 o;
    o.x = f2bf(v.x); o.y = f2bf(v.y); o.z = f2bf(v.z); o.w = f2bf(v.w);
    reinterpret_cast<ushort4*>(xb)[i] = o;
  } else {
    // 64 blocks x 256 threads cover 16384 = H*E entries
    int i = (b - TT * HH / 1024) * blockDim.x + threadIdx.x;
    int h = i >> 4, e = i & 15;
    wgT[e * HH + h] = wg[i];   // read coalesced; write 16 streams (64 KB total, one-shot)
  }
}

// ---------- transpose+cast weights: [K][N] fp32 -> [N][K] bf16 ----------
// R3 rewrite: 64x64 tile, 16B/lane global IO both directions, XOR-swizzled LDS
// (b64 accesses land at the LDS floor on both phases; old version was 2B/lane writes).
__global__ __launch_bounds__(256) void wtrans_kernel(
    const float* __restrict__ wgp, const float* __restrict__ wup,
    const float* __restrict__ wdp, u16* __restrict__ wgt,
    u16* __restrict__ wut, u16* __restrict__ wdt) {
  int z = blockIdx.z;
  int e = z & 15, t = z >> 4;
  const float* src; u16* dst; int K, N;
  if (t == 0)      { src = wgp + (size_t)e * HH * II; dst = wgt + (size_t)e * II * HH; K = HH; N = II; }
  else if (t == 1) { src = wup + (size_t)e * HH * II; dst = wut + (size_t)e * II * HH; K = HH; N = II; }
  else             { src = wdp + (size_t)e * II * HH; dst = wdt + (size_t)e * HH * II; K = II; N = HH; }
  int bx = blockIdx.x, by = blockIdx.y;      // bx: n-tile, by: k-tile
  if (bx * 64 >= N || by * 64 >= K) return;
  int K0 = by * 64, N0 = bx * 64;

  // LDS logical layout [n][k] (64x64 u16); k stored in 4-u16 groups, group index
  // XOR-swizzled by (n&15):  addr_u16(n,k) = n*64 + ((k>>2) ^ (n&15))*4 + (k&3)
  __shared__ u16 lds[64 * 64];

  int tid = threadIdx.x;
  // ---- phase 1: read 4k x 4n fp32 block per thread, cast, write 4x ds_write_b64 ----
  int KR  = tid >> 4;            // k-quad 0..15
  int nc4 = (tid & 15) * 4;      // n base
  float4 r[4];
#pragma unroll
  for (int ii = 0; ii < 4; ++ii)
    r[ii] = *reinterpret_cast<const float4*>(&src[(size_t)(K0 + 4 * KR + ii) * N + N0 + nc4]);
  u16 bv[4][4];   // [ii=k][j=n]
#pragma unroll
  for (int ii = 0; ii < 4; ++ii) {
    bv[ii][0] = f2bf(r[ii].x); bv[ii][1] = f2bf(r[ii].y);
    bv[ii][2] = f2bf(r[ii].z); bv[ii][3] = f2bf(r[ii].w);
  }
#pragma unroll
  for (int j = 0; j < 4; ++j) {
    int n = nc4 + j;
    int a = n * 64 + ((KR ^ (n & 15)) << 2);     // u16 units, 8B-aligned
    uint2 p;
    p.x = (unsigned)bv[0][j] | ((unsigned)bv[1][j] << 16);
    p.y = (unsigned)bv[2][j] | ((unsigned)bv[3][j] << 16);
    *reinterpret_cast<uint2*>(&lds[a]) = p;
  }
  __syncthreads();
  // ---- phase 2: per thread 2 chunks of 8 u16 -> 16B global stores ----
  int n  = tid >> 2;         // 0..63
  int kc = tid & 3;
  int m  = n & 15;
#pragma unroll
  for (int c = 0; c < 2; ++c) {
    int g = 4 * c + kc;      // 8-u16 chunk index 0..7
    int a0 = n * 64 + (((2 * g)     ^ m) << 2);
    int a1 = n * 64 + (((2 * g + 1) ^ m) << 2);
    uint2 q0 = *reinterpret_cast<const uint2*>(&lds[a0]);
    uint2 q1 = *reinterpret_cast<const uint2*>(&lds[a1]);
    uint4 st; st.x = q0.x; st.y = q0.y; st.z = q1.x; st.w = q1.y;
    *reinterpret_cast<uint4*>(&dst[(size_t)(N0 + n) * K + K0 + 8 * g]) = st;
  }
}

// ---------------- router: logits, top-4, per-token sel/weights. NO atomics. ----------------
// (R1 post-mortem: 8192 returning atomicAdds to one 64B line serialized at ~30cyc each = 105us.)
__global__ void router_kernel(const float* __restrict__ x, const float* __restrict__ wgT,
                              float* __restrict__ rl, unsigned* __restrict__ selmask,
                              float* __restrict__ wsel) {
  int lane = threadIdx.x & 63, wv = threadIdx.x >> 6;
  int t = blockIdx.x * 4 + wv;          // one wave per token
  const float* xr = x + (size_t)t * HH;
  float xv[16];
#pragma unroll
  for (int i = 0; i < 16; ++i) xv[i] = xr[lane + 64 * i];
  float lg[16];
#pragma unroll
  for (int e = 0; e < 16; ++e) {
    const float* wr = wgT + (size_t)e * HH;
    float p = 0.f;
#pragma unroll
    for (int i = 0; i < 16; ++i) p += xv[i] * wr[lane + 64 * i];
#pragma unroll
    for (int s = 32; s > 0; s >>= 1) p += __shfl_xor(p, s, 64);
    lg[e] = p;   // all lanes hold the full logit after butterfly
  }
  if (lane < 16) rl[(size_t)t * 16 + lane] = lg[lane];
  // top-4 (stable: earlier index wins ties, matches lax.top_k)
  unsigned mask = 0;
  int sel[4]; float bl[4];
#pragma unroll
  for (int k = 0; k < 4; ++k) {
    float best = -3.4e38f; int bi = 0;
#pragma unroll
    for (int e = 0; e < 16; ++e) {
      bool ok = !((mask >> e) & 1u) && (lg[e] > best);
      best = ok ? lg[e] : best;
      bi = ok ? e : bi;
    }
    mask |= 1u << bi;
    sel[k] = bi; bl[k] = best;
  }
  // normalized top-k softmax: full denominator cancels
  float mx = bl[0];
  float wk[4]; float s = 0.f;
#pragma unroll
  for (int k = 0; k < 4; ++k) { wk[k] = expf(bl[k] - mx); s += wk[k]; }
  float inv = 1.f / s;
  if (lane == 0) {
    selmask[t] = (unsigned)sel[0] | ((unsigned)sel[1] << 4) |
                 ((unsigned)sel[2] << 8) | ((unsigned)sel[3] << 12);
    float4 w4 = make_float4(wk[0] * inv, wk[1] * inv, wk[2] * inv, wk[3] * inv);
    reinterpret_cast<float4*>(wsel)[t] = w4;
  }
}

// ---------------- build per-expert lists: 1 block, 16 waves, ballot-compaction ----------------
// Deterministic, token-sorted, zero global atomics. Also computes counts+offsets.
__global__ void build_lists_kernel(const unsigned* __restrict__ selmask,
                                   const float* __restrict__ wsel,
                                   int* __restrict__ counts, int* __restrict__ offsets,
                                   int* __restrict__ tlist, float* __restrict__ wlist) {
  __shared__ int scnt[16];
  int lane = threadIdx.x & 63, e = threadIdx.x >> 6;   // wave e handles expert e
  int base = 0;
  for (int t0 = 0; t0 < TT; t0 += 64) {
    int t = t0 + lane;
    unsigned m = selmask[t];
    int k = -1;
#pragma unroll
    for (int j = 0; j < 4; ++j)
      if (((m >> (4 * j)) & 15u) == (unsigned)e) k = j;
    unsigned long long bal = __ballot(k >= 0);
    int pos = base + (int)__popcll(bal & ((1ull << lane) - 1ull));
    if (k >= 0) {
      tlist[e * TT + pos] = t;
      wlist[e * TT + pos] = wsel[t * 4 + k];
    }
    base += (int)__popcll(bal);
  }
  if (lane == 0) scnt[e] = base;
  __syncthreads();
  if (threadIdx.x == 0) {
    int s = 0;
    for (int i = 0; i < 16; ++i) { counts[i] = scnt[i]; offsets[i] = s; s += scnt[i]; }
    offsets[16] = s;
  }
}

// ---------------- gate+up fused GEMM -> hidden (bf16, pre-scaled by routing weight) ----------------
// Tile 128x128, BK=64, 4 waves 2x2, each wave 64x64 (4x4 frags of 16x16x32 bf16 MFMA).
__global__ __launch_bounds__(256, 2) void gateup_kernel(
    const u16* __restrict__ xb, const u16* __restrict__ wgt, const u16* __restrict__ wut,
    const int* __restrict__ counts, const int* __restrict__ offsets,
    const int* __restrict__ tlist, const float* __restrict__ wlist,
    u16* __restrict__ hidden) {
  int e = blockIdx.z, mt = blockIdx.y, nt = blockIdx.x;
  int cnt = counts[e];
  if (mt * 128 >= cnt) return;
  __shared__ u16 As[128 * 64];   // [m][k]
  __shared__ u16 Bg[128 * 64];   // [n][k]
  __shared__ u16 Bu[128 * 64];
  int tid = threadIdx.x, lane = tid & 63, wv = tid >> 6;
  int wm = wv >> 1, wn = wv & 1;
  int srow = lane >> 3;            // staging: 8 lanes/row, 16B each
  int scol = (lane & 7) * 8;       // bf16 elements
  const u16* wgE = wgt + (size_t)e * II * HH;
  const u16* wuE = wut + (size_t)e * II * HH;
  const u16* gA[4]; const u16* gBg[4]; const u16* gBu[4];
#pragma unroll
  for (int c = 0; c < 4; ++c) {
    int chunk = c * 4 + wv;                 // 16 chunks of 8 rows per tile
    int m = chunk * 8 + srow;
    int mi = mt * 128 + m; if (mi >= cnt) mi = cnt - 1;   // clamp pad rows
    int tok = tlist[e * TT + mi];           // row gather via per-lane global addr
    gA[c]  = xb  + (size_t)tok * HH + scol;
    int n = nt * 128 + chunk * 8 + srow;
    gBg[c] = wgE + (size_t)n * HH + scol;
    gBu[c] = wuE + (size_t)n * HH + scol;
  }
  f32x4 accG[4][4] = {}; f32x4 accU[4][4] = {};
  for (int k0 = 0; k0 < HH; k0 += 64) {
#pragma unroll
    for (int c = 0; c < 4; ++c) {
      int chunk = c * 4 + wv;
      gl2lds16(gA[c]  + k0, &As[chunk * 512]);
      gl2lds16(gBg[c] + k0, &Bg[chunk * 512]);
      gl2lds16(gBu[c] + k0, &Bu[chunk * 512]);
    }
    __syncthreads();
#pragma unroll
    for (int kk = 0; kk < 64; kk += 32) {
      s16x8 a[4], bg[4], bu[4];
      int koff = kk + (lane >> 4) * 8;
#pragma unroll
      for (int f = 0; f < 4; ++f) {
        a[f]  = *reinterpret_cast<const s16x8*>(&As[(wm * 64 + f * 16 + (lane & 15)) * 64 + koff]);
        bg[f] = *reinterpret_cast<const s16x8*>(&Bg[(wn * 64 + f * 16 + (lane & 15)) * 64 + koff]);
        bu[f] = *reinterpret_cast<const s16x8*>(&Bu[(wn * 64 + f * 16 + (lane & 15)) * 64 + koff]);
      }
#pragma unroll
      for (int fm = 0; fm < 4; ++fm)
#pragma unroll
        for (int fn = 0; fn < 4; ++fn) {
          accG[fm][fn] = __builtin_amdgcn_mfma_f32_16x16x32_bf16(a[fm], bg[fn], accG[fm][fn], 0, 0, 0);
          accU[fm][fn] = __builtin_amdgcn_mfma_f32_16x16x32_bf16(a[fm], bu[fn], accU[fm][fn], 0, 0, 0);
        }
    }
    __syncthreads();
  }
  // epilogue: hidden = w_route * silu(g) * u   (C/D: col=lane&15, row=quad*4+reg)
  int hb = offsets[e];
  int quad = lane >> 4, colc = lane & 15;
#pragma unroll
  for (int fm = 0; fm < 4; ++fm) {
#pragma unroll
    for (int r = 0; r < 4; ++r) {
      int mi = mt * 128 + wm * 64 + fm * 16 + quad * 4 + r;
      if (mi < cnt) {
        float wr = wlist[e * TT + mi];
        u16* hrow = hidden + (size_t)(hb + mi) * II + nt * 128 + wn * 64;
#pragma unroll
        for (int fn = 0; fn < 4; ++fn) {
          float g = accG[fm][fn][r], u = accU[fm][fn][r];
          float hval = wr * u * g / (1.f + expf(-g));
          hrow[fn * 16 + colc] = f2bf(hval);
        }
      }
    }
  }
}

// ---------------- down GEMM: hidden @ wd^T -> atomicAdd into out ----------------
__global__ __launch_bounds__(256, 2) void down_kernel(
    const u16* __restrict__ hidden, const u16* __restrict__ wdt,
    const int* __restrict__ counts, const int* __restrict__ offsets,
    const int* __restrict__ tlist, float* __restrict__ out) {
  int e = blockIdx.z, mt = blockIdx.y, nt = blockIdx.x;
  int cnt = counts[e];
  if (mt * 128 >= cnt) return;
  int hb = offsets[e];
  __shared__ u16 As[128 * 64];
  __shared__ u16 Bs[128 * 64];
  int tid = threadIdx.x, lane = tid & 63, wv = tid >> 6;
  int wm = wv >> 1, wn = wv & 1;
  int srow = lane >> 3, scol = (lane & 7) * 8;
  const u16* wdE = wdt + (size_t)e * HH * II;
  const u16* gA[4]; const u16* gB[4];
#pragma unroll
  for (int c = 0; c < 4; ++c) {
    int chunk = c * 4 + wv;
    int row = hb + mt * 128 + chunk * 8 + srow;
    if (row > 8191) row = 8191;   // clamp pad rows into the hidden buffer
    gA[c] = hidden + (size_t)row * II + scol;
    int n = nt * 128 + chunk * 8 + srow;
    gB[c] = wdE + (size_t)n * II + scol;
  }
  f32x4 acc[4][4] = {};
  for (int k0 = 0; k0 < II; k0 += 64) {
#pragma unroll
    for (int c = 0; c < 4; ++c) {
      int chunk = c * 4 + wv;
      gl2lds16(gA[c] + k0, &As[chunk * 512]);
      gl2lds16(gB[c] + k0, &Bs[chunk * 512]);
    }
    __syncthreads();
#pragma unroll
    for (int kk = 0; kk < 64; kk += 32) {
      s16x8 a[4], b[4];
      int koff = kk + (lane >> 4) * 8;
#pragma unroll
      for (int f = 0; f < 4; ++f) {
        a[f] = *reinterpret_cast<const s16x8*>(&As[(wm * 64 + f * 16 + (lane & 15)) * 64 + koff]);
        b[f] = *reinterpret_cast<const s16x8*>(&Bs[(wn * 64 + f * 16 + (lane & 15)) * 64 + koff]);
      }
#pragma unroll
      for (int fm = 0; fm < 4; ++fm)
#pragma unroll
        for (int fn = 0; fn < 4; ++fn)
          acc[fm][fn] = __builtin_amdgcn_mfma_f32_16x16x32_bf16(a[fm], b[fn], acc[fm][fn], 0, 0, 0);
    }
    __syncthreads();
  }
  int quad = lane >> 4, colc = lane & 15;
#pragma unroll
  for (int fm = 0; fm < 4; ++fm) {
#pragma unroll
    for (int r = 0; r < 4; ++r) {
      int mi = mt * 128 + wm * 64 + fm * 16 + quad * 4 + r;
      if (mi < cnt) {
        int tok = tlist[e * TT + mi];
        float* orow = out + (size_t)tok * HH + nt * 128 + wn * 64;
#pragma unroll
        for (int fn = 0; fn < 4; ++fn)
          atomicAdd(&orow[fn * 16 + colc], acc[fm][fn][r]);
      }
    }
  }
}

extern "C" void kernel_launch(void* const* d_in, const int* in_sizes, int n_in,
                              void* d_out, int out_size, void* d_ws, size_t ws_size,
                              hipStream_t stream) {
  const float* x   = (const float*)d_in[0];   // [1,2048,1024]
  const float* wg  = (const float*)d_in[1];   // [1024,16]
  const float* wgp = (const float*)d_in[2];   // [16,1024,512]
  const float* wup = (const float*)d_in[3];   // [16,1024,512]
  const float* wdp = (const float*)d_in[4];   // [16,512,1024]
  float* out = (float*)d_out;                 // [2048*1024] then router_logits [2048*16]
  float* rl  = out + (size_t)TT * HH;

  char* w = (char*)d_ws;
  int*      counts  = (int*)(w + 0);                  // 16 ints
  int*      offsets = (int*)(w + 64);                 // 17 ints
  unsigned* selmask = (unsigned*)(w + 1024);          // [T] packed 4x4-bit expert ids
  float*    wsel    = (float*)(w + 1024 + 8192);      // [T][4] normalized weights
  int*      tlist   = (int*)(w + 49152);              // [E][T] token ids
  float*    wlist   = (float*)(w + 49152 + 131072);   // [E][T] routing weights
  float*    wgT     = (float*)(w + 49152 + 262144);   // [E][H] fp32 transposed router weights
  u16*      xb      = (u16*)(w + 49152 + 262144 + 65536);   // [T][H] bf16
  u16*      wgt     = xb  + (size_t)TT * HH;          // [E][I][H] bf16 (transposed)
  u16*      wut     = wgt + (size_t)EE * II * HH;
  u16*      wdt     = wut + (size_t)EE * II * HH;     // [E][H][I] bf16 (transposed)
  u16*      hidden  = wdt + (size_t)EE * HH * II;     // [8192][I] bf16

  hipMemsetAsync(out, 0, (size_t)TT * HH * sizeof(float), stream);

  hipLaunchKernelGGL(cast_x_kernel, dim3(TT * HH / 1024 + 64), dim3(256), 0, stream,
                     x, xb, wg, wgT);
  hipLaunchKernelGGL(wtrans_kernel, dim3(16, 16, 48), dim3(256), 0, stream,
                     wgp, wup, wdp, wgt, wut, wdt);
  hipLaunchKernelGGL(router_kernel, dim3(TT / 4), dim3(256), 0, stream,
                     x, wgT, rl, selmask, wsel);
  hipLaunchKernelGGL(build_lists_kernel, dim3(1), dim3(1024), 0, stream,
                     selmask, wsel, counts, offsets, tlist, wlist);
  hipLaunchKernelGGL(gateup_kernel, dim3(4, 16, 16), dim3(256), 0, stream,
                     xb, wgt, wut, counts, offsets, tlist, wlist, hidden);
  hipLaunchKernelGGL(down_kernel, dim3(8, 16, 16), dim3(256), 0, stream,
                     hidden, wdt, counts, offsets, tlist, out);
}

// Round 5
// 255.849 us; speedup vs baseline: 1.3505x; 1.0264x over previous
//
#include <hip/hip_runtime.h>
#include <math.h>

// Qwen3 MoE sparse block, MI355X/gfx950.
// Sizes fixed by the reference: T=2048 tokens, H=1024, E=16, I=512, top-4.
constexpr int TT = 2048;   // tokens
constexpr int HH = 1024;   // hidden
constexpr int EE = 16;     // experts
constexpr int II = 512;    // intermediate

typedef unsigned short u16;
typedef short s16x8 __attribute__((ext_vector_type(8)));   // 8 bf16 for MFMA A/B
typedef float f32x4 __attribute__((ext_vector_type(4)));   // MFMA C/D

__device__ __forceinline__ u16 f2bf(float f) {
  unsigned u = __float_as_uint(f);
  u = (u + 0x7fffu + ((u >> 16) & 1u)) >> 16;   // round-to-nearest-even
  return (u16)u;
}

// async global->LDS, 16B per lane; lds base must be wave-uniform (HW adds lane*16)
__device__ __forceinline__ void gl2lds16(const void* g, void* l) {
  __builtin_amdgcn_global_load_lds(
      (const __attribute__((address_space(1))) unsigned*)g,
      (__attribute__((address_space(3))) unsigned*)l, 16, 0, 0);
}

// LDS k-group XOR swizzle (R4): tiles are [row][8 groups of 8 u16]; logical group g
// of row m lives at physical group g^(m&7). Staging keeps lane->LDS fixed and permutes
// the *global* source k-offset instead (global_load_lds can't scatter). Fragment reads
// then spread a quarter-wave across all 32 banks (2-way alias = free) instead of 16-way.

// ---------------- cast x (fp32 -> bf16) + transpose wg -> wgT [E][H] fp32 ----------------
__global__ void cast_x_kernel(const float* __restrict__ x, u16* __restrict__ xb,
                              const float* __restrict__ wg, float* __restrict__ wgT) {
  int b = blockIdx.x;
  if (b < TT * HH / 1024) {
    int i = b * blockDim.x + threadIdx.x;
    float4 v = reinterpret_cast<const float4*>(x)[i];
    ushort4 o;
    o.x = f2bf(v.x); o.y = f2bf(v.y); o.z = f2bf(v.z); o.w = f2bf(v.w);
    reinterpret_cast<ushort4*>(xb)[i] = o;
  } else {
    // 64 blocks x 256 threads cover 16384 = H*E entries
    int i = (b - TT * HH / 1024) * blockDim.x + threadIdx.x;
    int h = i >> 4, e = i & 15;
    wgT[e * HH + h] = wg[i];   // read coalesced; write 16 streams (64 KB total, one-shot)
  }
}

// ---------- transpose+cast weights: [K][N] fp32 -> [N][K] bf16 ----------
// R3 rewrite: 64x64 tile, 16B/lane global IO both directions, XOR-swizzled LDS
// (b64 accesses land at the LDS floor on both phases; old version was 2B/lane writes).
__global__ __launch_bounds__(256) void wtrans_kernel(
    const float* __restrict__ wgp, const float* __restrict__ wup,
    const float* __restrict__ wdp, u16* __restrict__ wgt,
    u16* __restrict__ wut, u16* __restrict__ wdt) {
  int z = blockIdx.z;
  int e = z & 15, t = z >> 4;
  const float* src; u16* dst; int K, N;
  if (t == 0)      { src = wgp + (size_t)e * HH * II; dst = wgt + (size_t)e * II * HH; K = HH; N = II; }
  else if (t == 1) { src = wup + (size_t)e * HH * II; dst = wut + (size_t)e * II * HH; K = HH; N = II; }
  else             { src = wdp + (size_t)e * II * HH; dst = wdt + (size_t)e * HH * II; K = II; N = HH; }
  int bx = blockIdx.x, by = blockIdx.y;      // bx: n-tile, by: k-tile
  if (bx * 64 >= N || by * 64 >= K) return;
  int K0 = by * 64, N0 = bx * 64;

  // LDS logical layout [n][k] (64x64 u16); k stored in 4-u16 groups, group index
  // XOR-swizzled by (n&15):  addr_u16(n,k) = n*64 + ((k>>2) ^ (n&15))*4 + (k&3)
  __shared__ u16 lds[64 * 64];

  int tid = threadIdx.x;
  // ---- phase 1: read 4k x 4n fp32 block per thread, cast, write 4x ds_write_b64 ----
  int KR  = tid >> 4;            // k-quad 0..15
  int nc4 = (tid & 15) * 4;      // n base
  float4 r[4];
#pragma unroll
  for (int ii = 0; ii < 4; ++ii)
    r[ii] = *reinterpret_cast<const float4*>(&src[(size_t)(K0 + 4 * KR + ii) * N + N0 + nc4]);
  u16 bv[4][4];   // [ii=k][j=n]
#pragma unroll
  for (int ii = 0; ii < 4; ++ii) {
    bv[ii][0] = f2bf(r[ii].x); bv[ii][1] = f2bf(r[ii].y);
    bv[ii][2] = f2bf(r[ii].z); bv[ii][3] = f2bf(r[ii].w);
  }
#pragma unroll
  for (int j = 0; j < 4; ++j) {
    int n = nc4 + j;
    int a = n * 64 + ((KR ^ (n & 15)) << 2);     // u16 units, 8B-aligned
    uint2 p;
    p.x = (unsigned)bv[0][j] | ((unsigned)bv[1][j] << 16);
    p.y = (unsigned)bv[2][j] | ((unsigned)bv[3][j] << 16);
    *reinterpret_cast<uint2*>(&lds[a]) = p;
  }
  __syncthreads();
  // ---- phase 2: per thread 2 chunks of 8 u16 -> 16B global stores ----
  int n  = tid >> 2;         // 0..63
  int kc = tid & 3;
  int m  = n & 15;
#pragma unroll
  for (int c = 0; c < 2; ++c) {
    int g = 4 * c + kc;      // 8-u16 chunk index 0..7
    int a0 = n * 64 + (((2 * g)     ^ m) << 2);
    int a1 = n * 64 + (((2 * g + 1) ^ m) << 2);
    uint2 q0 = *reinterpret_cast<const uint2*>(&lds[a0]);
    uint2 q1 = *reinterpret_cast<const uint2*>(&lds[a1]);
    uint4 st; st.x = q0.x; st.y = q0.y; st.z = q1.x; st.w = q1.y;
    *reinterpret_cast<uint4*>(&dst[(size_t)(N0 + n) * K + K0 + 8 * g]) = st;
  }
}

// ---------------- router: logits, top-4, per-token sel/weights. NO atomics. ----------------
// (R1 post-mortem: 8192 returning atomicAdds to one 64B line serialized at ~30cyc each = 105us.)
__global__ void router_kernel(const float* __restrict__ x, const float* __restrict__ wgT,
                              float* __restrict__ rl, unsigned* __restrict__ selmask,
                              float* __restrict__ wsel) {
  int lane = threadIdx.x & 63, wv = threadIdx.x >> 6;
  int t = blockIdx.x * 4 + wv;          // one wave per token
  const float* xr = x + (size_t)t * HH;
  float xv[16];
#pragma unroll
  for (int i = 0; i < 16; ++i) xv[i] = xr[lane + 64 * i];
  float lg[16];
#pragma unroll
  for (int e = 0; e < 16; ++e) {
    const float* wr = wgT + (size_t)e * HH;
    float p = 0.f;
#pragma unroll
    for (int i = 0; i < 16; ++i) p += xv[i] * wr[lane + 64 * i];
#pragma unroll
    for (int s = 32; s > 0; s >>= 1) p += __shfl_xor(p, s, 64);
    lg[e] = p;   // all lanes hold the full logit after butterfly
  }
  if (lane < 16) rl[(size_t)t * 16 + lane] = lg[lane];
  // top-4 (stable: earlier index wins ties, matches lax.top_k)
  unsigned mask = 0;
  int sel[4]; float bl[4];
#pragma unroll
  for (int k = 0; k < 4; ++k) {
    float best = -3.4e38f; int bi = 0;
#pragma unroll
    for (int e = 0; e < 16; ++e) {
      bool ok = !((mask >> e) & 1u) && (lg[e] > best);
      best = ok ? lg[e] : best;
      bi = ok ? e : bi;
    }
    mask |= 1u << bi;
    sel[k] = bi; bl[k] = best;
  }
  // normalized top-k softmax: full denominator cancels
  float mx = bl[0];
  float wk[4]; float s = 0.f;
#pragma unroll
  for (int k = 0; k < 4; ++k) { wk[k] = expf(bl[k] - mx); s += wk[k]; }
  float inv = 1.f / s;
  if (lane == 0) {
    selmask[t] = (unsigned)sel[0] | ((unsigned)sel[1] << 4) |
                 ((unsigned)sel[2] << 8) | ((unsigned)sel[3] << 12);
    float4 w4 = make_float4(wk[0] * inv, wk[1] * inv, wk[2] * inv, wk[3] * inv);
    reinterpret_cast<float4*>(wsel)[t] = w4;
  }
}

// ---------------- build per-expert lists: 1 block, 16 waves, ballot-compaction ----------------
// Deterministic, token-sorted, zero global atomics. Also computes counts+offsets.
__global__ void build_lists_kernel(const unsigned* __restrict__ selmask,
                                   const float* __restrict__ wsel,
                                   int* __restrict__ counts, int* __restrict__ offsets,
                                   int* __restrict__ tlist, float* __restrict__ wlist) {
  __shared__ int scnt[16];
  int lane = threadIdx.x & 63, e = threadIdx.x >> 6;   // wave e handles expert e
  int base = 0;
  for (int t0 = 0; t0 < TT; t0 += 64) {
    int t = t0 + lane;
    unsigned m = selmask[t];
    int k = -1;
#pragma unroll
    for (int j = 0; j < 4; ++j)
      if (((m >> (4 * j)) & 15u) == (unsigned)e) k = j;
    unsigned long long bal = __ballot(k >= 0);
    int pos = base + (int)__popcll(bal & ((1ull << lane) - 1ull));
    if (k >= 0) {
      tlist[e * TT + pos] = t;
      wlist[e * TT + pos] = wsel[t * 4 + k];
    }
    base += (int)__popcll(bal);
  }
  if (lane == 0) scnt[e] = base;
  __syncthreads();
  if (threadIdx.x == 0) {
    int s = 0;
    for (int i = 0; i < 16; ++i) { counts[i] = scnt[i]; offsets[i] = s; s += scnt[i]; }
    offsets[16] = s;
  }
}

// ---------------- gate+up fused GEMM -> hidden (bf16, pre-scaled by routing weight) ----------------
// R4: tile 128(M)x64(N), BK=64, swizzled LDS. 4 waves 2x2: wave = 64 rows x 32 cols
// (4x2 frags of 16x16x32). nt=8 doubles working blocks -> 2 blocks/CU.
__global__ __launch_bounds__(256, 2) void gateup_kernel(
    const u16* __restrict__ xb, const u16* __restrict__ wgt, const u16* __restrict__ wut,
    const int* __restrict__ counts, const int* __restrict__ offsets,
    const int* __restrict__ tlist, const float* __restrict__ wlist,
    u16* __restrict__ hidden) {
  int e = blockIdx.z, mt = blockIdx.y, nt = blockIdx.x;   // nt 0..7 (64 cols each)
  int cnt = counts[e];
  if (mt * 128 >= cnt) return;
  __shared__ u16 As[128 * 64];   // [m][k] swizzled
  __shared__ u16 Bg[64 * 64];    // [n][k] swizzled
  __shared__ u16 Bu[64 * 64];
  int tid = threadIdx.x, lane = tid & 63, wv = tid >> 6;
  int wm = wv >> 1, wn = wv & 1;
  int srow = lane >> 3;                     // staging row within 8-row chunk
  int scol = (((lane & 7) ^ srow)) * 8;     // swizzled global k-offset (u16)
  const u16* wgE = wgt + (size_t)e * II * HH;
  const u16* wuE = wut + (size_t)e * II * HH;
  // 32 chunks of 8 rows: A=0..15, Bg=16..23, Bu=24..31; chunk = c*4+wv
  const u16* gp[8];
#pragma unroll
  for (int c = 0; c < 8; ++c) {
    int chunk = c * 4 + wv;
    const u16* p;
    if (chunk < 16) {
      int mi = mt * 128 + chunk * 8 + srow; if (mi >= cnt) mi = cnt - 1;
      int tok = tlist[e * TT + mi];
      p = xb + (size_t)tok * HH + scol;
    } else if (chunk < 24) {
      int n = nt * 64 + (chunk - 16) * 8 + srow;
      p = wgE + (size_t)n * HH + scol;
    } else {
      int n = nt * 64 + (chunk - 24) * 8 + srow;
      p = wuE + (size_t)n * HH + scol;
    }
    gp[c] = p;
  }
  f32x4 accG[4][2] = {}; f32x4 accU[4][2] = {};
  int quad = lane >> 4, colc = lane & 15;
  for (int k0 = 0; k0 < HH; k0 += 64) {
#pragma unroll
    for (int c = 0; c < 8; ++c) {
      int chunk = c * 4 + wv;
      u16* dst = (chunk < 16) ? &As[chunk * 512]
               : (chunk < 24) ? &Bg[(chunk - 16) * 512]
                              : &Bu[(chunk - 24) * 512];
      gl2lds16(gp[c] + k0, dst);
    }
    __syncthreads();
#pragma unroll
    for (int kk = 0; kk < 64; kk += 32) {
      int gl = (kk >> 3) + quad;            // logical k-group
      s16x8 a[4], bg[2], bu[2];
#pragma unroll
      for (int f = 0; f < 4; ++f) {
        int m = wm * 64 + f * 16 + colc;
        a[f] = *reinterpret_cast<const s16x8*>(&As[m * 64 + ((gl ^ (m & 7)) << 3)]);
      }
#pragma unroll
      for (int f = 0; f < 2; ++f) {
        int n = wn * 32 + f * 16 + colc;
        bg[f] = *reinterpret_cast<const s16x8*>(&Bg[n * 64 + ((gl ^ (n & 7)) << 3)]);
        bu[f] = *reinterpret_cast<const s16x8*>(&Bu[n * 64 + ((gl ^ (n & 7)) << 3)]);
      }
#pragma unroll
      for (int fm = 0; fm < 4; ++fm)
#pragma unroll
        for (int fn = 0; fn < 2; ++fn) {
          accG[fm][fn] = __builtin_amdgcn_mfma_f32_16x16x32_bf16(a[fm], bg[fn], accG[fm][fn], 0, 0, 0);
          accU[fm][fn] = __builtin_amdgcn_mfma_f32_16x16x32_bf16(a[fm], bu[fn], accU[fm][fn], 0, 0, 0);
        }
    }
    __syncthreads();
  }
  // epilogue: hidden = w_route * silu(g) * u   (C/D: col=lane&15, row=quad*4+reg)
  int hb = offsets[e];
#pragma unroll
  for (int fm = 0; fm < 4; ++fm) {
#pragma unroll
    for (int r = 0; r < 4; ++r) {
      int mi = mt * 128 + wm * 64 + fm * 16 + quad * 4 + r;
      if (mi < cnt) {
        float wr = wlist[e * TT + mi];
        u16* hrow = hidden + (size_t)(hb + mi) * II + nt * 64 + wn * 32;
#pragma unroll
        for (int fn = 0; fn < 2; ++fn) {
          float g = accG[fm][fn][r], u = accU[fm][fn][r];
          float hval = wr * u * g / (1.f + expf(-g));
          hrow[fn * 16 + colc] = f2bf(hval);
        }
      }
    }
  }
}

// ---------------- down GEMM: hidden @ wd^T -> atomicAdd into out ----------------
// R4: swizzled LDS (same conflict fix). Tile 128x128, 4 waves 2x2 (64x64 each).
__global__ __launch_bounds__(256, 2) void down_kernel(
    const u16* __restrict__ hidden, const u16* __restrict__ wdt,
    const int* __restrict__ counts, const int* __restrict__ offsets,
    const int* __restrict__ tlist, float* __restrict__ out) {
  int e = blockIdx.z, mt = blockIdx.y, nt = blockIdx.x;
  int cnt = counts[e];
  if (mt * 128 >= cnt) return;
  int hb = offsets[e];
  __shared__ u16 As[128 * 64];
  __shared__ u16 Bs[128 * 64];
  int tid = threadIdx.x, lane = tid & 63, wv = tid >> 6;
  int wm = wv >> 1, wn = wv & 1;
  int srow = lane >> 3;
  int scol = (((lane & 7) ^ srow)) * 8;     // swizzled global k-offset
  const u16* wdE = wdt + (size_t)e * HH * II;
  const u16* gA[4]; const u16* gB[4];
#pragma unroll
  for (int c = 0; c < 4; ++c) {
    int chunk = c * 4 + wv;
    int row = hb + mt * 128 + chunk * 8 + srow;
    if (row > 8191) row = 8191;   // clamp pad rows into the hidden buffer
    gA[c] = hidden + (size_t)row * II + scol;
    int n = nt * 128 + chunk * 8 + srow;
    gB[c] = wdE + (size_t)n * II + scol;
  }
  f32x4 acc[4][4] = {};
  int quad = lane >> 4, colc = lane & 15;
  for (int k0 = 0; k0 < II; k0 += 64) {
#pragma unroll
    for (int c = 0; c < 4; ++c) {
      int chunk = c * 4 + wv;
      gl2lds16(gA[c] + k0, &As[chunk * 512]);
      gl2lds16(gB[c] + k0, &Bs[chunk * 512]);
    }
    __syncthreads();
#pragma unroll
    for (int kk = 0; kk < 64; kk += 32) {
      int gl = (kk >> 3) + quad;
      s16x8 a[4], b[4];
#pragma unroll
      for (int f = 0; f < 4; ++f) {
        int m = wm * 64 + f * 16 + colc;
        int n = wn * 64 + f * 16 + colc;
        a[f] = *reinterpret_cast<const s16x8*>(&As[m * 64 + ((gl ^ (m & 7)) << 3)]);
        b[f] = *reinterpret_cast<const s16x8*>(&Bs[n * 64 + ((gl ^ (n & 7)) << 3)]);
      }
#pragma unroll
      for (int fm = 0; fm < 4; ++fm)
#pragma unroll
        for (int fn = 0; fn < 4; ++fn)
          acc[fm][fn] = __builtin_amdgcn_mfma_f32_16x16x32_bf16(a[fm], b[fn], acc[fm][fn], 0, 0, 0);
    }
    __syncthreads();
  }
#pragma unroll
  for (int fm = 0; fm < 4; ++fm) {
#pragma unroll
    for (int r = 0; r < 4; ++r) {
      int mi = mt * 128 + wm * 64 + fm * 16 + quad * 4 + r;
      if (mi < cnt) {
        int tok = tlist[e * TT + mi];
        float* orow = out + (size_t)tok * HH + nt * 128 + wn * 64;
#pragma unroll
        for (int fn = 0; fn < 4; ++fn)
          atomicAdd(&orow[fn * 16 + colc], acc[fm][fn][r]);
      }
    }
  }
}

extern "C" void kernel_launch(void* const* d_in, const int* in_sizes, int n_in,
                              void* d_out, int out_size, void* d_ws, size_t ws_size,
                              hipStream_t stream) {
  const float* x   = (const float*)d_in[0];   // [1,2048,1024]
  const float* wg  = (const float*)d_in[1];   // [1024,16]
  const float* wgp = (const float*)d_in[2];   // [16,1024,512]
  const float* wup = (const float*)d_in[3];   // [16,1024,512]
  const float* wdp = (const float*)d_in[4];   // [16,512,1024]
  float* out = (float*)d_out;                 // [2048*1024] then router_logits [2048*16]
  float* rl  = out + (size_t)TT * HH;

  char* w = (char*)d_ws;
  int*      counts  = (int*)(w + 0);                  // 16 ints
  int*      offsets = (int*)(w + 64);                 // 17 ints
  unsigned* selmask = (unsigned*)(w + 1024);          // [T] packed 4x4-bit expert ids
  float*    wsel    = (float*)(w + 1024 + 8192);      // [T][4] normalized weights
  int*      tlist   = (int*)(w + 49152);              // [E][T] token ids
  float*    wlist   = (float*)(w + 49152 + 131072);   // [E][T] routing weights
  float*    wgT     = (float*)(w + 49152 + 262144);   // [E][H] fp32 transposed router weights
  u16*      xb      = (u16*)(w + 49152 + 262144 + 65536);   // [T][H] bf16
  u16*      wgt     = xb  + (size_t)TT * HH;          // [E][I][H] bf16 (transposed)
  u16*      wut     = wgt + (size_t)EE * II * HH;
  u16*      wdt     = wut + (size_t)EE * II * HH;     // [E][H][I] bf16 (transposed)
  u16*      hidden  = wdt + (size_t)EE * HH * II;     // [8192][I] bf16

  hipMemsetAsync(out, 0, (size_t)TT * HH * sizeof(float), stream);

  hipLaunchKernelGGL(cast_x_kernel, dim3(TT * HH / 1024 + 64), dim3(256), 0, stream,
                     x, xb, wg, wgT);
  hipLaunchKernelGGL(wtrans_kernel, dim3(16, 16, 48), dim3(256), 0, stream,
                     wgp, wup, wdp, wgt, wut, wdt);
  hipLaunchKernelGGL(router_kernel, dim3(TT / 4), dim3(256), 0, stream,
                     x, wgT, rl, selmask, wsel);
  hipLaunchKernelGGL(build_lists_kernel, dim3(1), dim3(1024), 0, stream,
                     selmask, wsel, counts, offsets, tlist, wlist);
  hipLaunchKernelGGL(gateup_kernel, dim3(8, 16, 16), dim3(256), 0, stream,
                     xb, wgt, wut, counts, offsets, tlist, wlist, hidden);
  hipLaunchKernelGGL(down_kernel, dim3(8, 16, 16), dim3(256), 0, stream,
                     hidden, wdt, counts, offsets, tlist, out);
}

// Round 6
// 244.204 us; speedup vs baseline: 1.4149x; 1.0477x over previous
//
#include <hip/hip_runtime.h>
#include <math.h>

// Qwen3 MoE sparse block, MI355X/gfx950.
// Sizes fixed by the reference: T=2048 tokens, H=1024, E=16, I=512, top-4.
constexpr int TT = 2048;   // tokens
constexpr int HH = 1024;   // hidden
constexpr int EE = 16;     // experts
constexpr int II = 512;    // intermediate

typedef unsigned short u16;
typedef short s16x8 __attribute__((ext_vector_type(8)));   // 8 bf16 for MFMA A/B
typedef float f32x4 __attribute__((ext_vector_type(4)));   // MFMA C/D

__device__ __forceinline__ u16 f2bf(float f) {
  unsigned u = __float_as_uint(f);
  u = (u + 0x7fffu + ((u >> 16) & 1u)) >> 16;   // round-to-nearest-even
  return (u16)u;
}
__device__ __forceinline__ float bf2f(u16 b) {
  return __uint_as_float(((unsigned)b) << 16);
}

// async global->LDS, 16B per lane; lds base must be wave-uniform (HW adds lane*16)
__device__ __forceinline__ void gl2lds16(const void* g, void* l) {
  __builtin_amdgcn_global_load_lds(
      (const __attribute__((address_space(1))) unsigned*)g,
      (__attribute__((address_space(3))) unsigned*)l, 16, 0, 0);
}

// ---------------- cast x (fp32 -> bf16) + transpose wg -> wgT [E][H] fp32 ----------------
__global__ void cast_x_kernel(const float* __restrict__ x, u16* __restrict__ xb,
                              const float* __restrict__ wg, float* __restrict__ wgT) {
  int b = blockIdx.x;
  if (b < TT * HH / 1024) {
    int i = b * blockDim.x + threadIdx.x;
    float4 v = reinterpret_cast<const float4*>(x)[i];
    ushort4 o;
    o.x = f2bf(v.x); o.y = f2bf(v.y); o.z = f2bf(v.z); o.w = f2bf(v.w);
    reinterpret_cast<ushort4*>(xb)[i] = o;
  } else {
    // 64 blocks x 256 threads cover 16384 = H*E entries
    int i = (b - TT * HH / 1024) * blockDim.x + threadIdx.x;
    int h = i >> 4, e = i & 15;
    wgT[e * HH + h] = wg[i];   // read coalesced; write 16 streams (64 KB total, one-shot)
  }
}

// ---------- transpose+cast weights: [K][N] fp32 -> [N][K] bf16 ----------
// R5 v3: NO LDS, no barriers. Thread owns 4 n x 8 k: 8x float4 coalesced reads
// (1 KB/wave/instr), register pack, 4x 16B stores (lines completed within block).
// (R4's LDS version: row stride 128 B == 32 banks -> swizzle broken, 1.77M conflicts,
//  and small-block load->barrier->store chains capped it at 2.3 TB/s.)
__global__ __launch_bounds__(256) void wtrans_kernel(
    const float* __restrict__ wgp, const float* __restrict__ wup,
    const float* __restrict__ wdp, u16* __restrict__ wgt,
    u16* __restrict__ wut, u16* __restrict__ wdt) {
  int bid = blockIdx.x;          // 3072 = 48 regions x 64 blocks
  int z = bid >> 6, lb = bid & 63;
  int e = z & 15, t = z >> 4;
  const float* src; u16* dst; int K, N;
  if (t == 0)      { src = wgp + (size_t)e * HH * II; dst = wgt + (size_t)e * II * HH; K = HH; N = II; }
  else if (t == 1) { src = wup + (size_t)e * HH * II; dst = wut + (size_t)e * II * HH; K = HH; N = II; }
  else             { src = wdp + (size_t)e * II * HH; dst = wdt + (size_t)e * HH * II; K = II; N = HH; }
  int nTiles = N >> 8;                  // 256-wide n tiles: 2 (N=512) or 4 (N=1024)
  int n0 = (lb % nTiles) * 256;
  int k0 = (lb / nTiles) * 32;          // 32-deep k tiles
  int tid = threadIdx.x;
  int ng = (tid & 63) * 4;              // 4 consecutive n per thread
  int kk = k0 + (tid >> 6) * 8;         // 8 consecutive k per thread
  float4 r[8];
#pragma unroll
  for (int j = 0; j < 8; ++j)
    r[j] = *reinterpret_cast<const float4*>(&src[(size_t)(kk + j) * N + n0 + ng]);
#pragma unroll
  for (int nn = 0; nn < 4; ++nn) {
    float v[8];
#pragma unroll
    for (int j = 0; j < 8; ++j)
      v[j] = (nn == 0) ? r[j].x : (nn == 1) ? r[j].y : (nn == 2) ? r[j].z : r[j].w;
    uint4 st;
    st.x = (unsigned)f2bf(v[0]) | ((unsigned)f2bf(v[1]) << 16);
    st.y = (unsigned)f2bf(v[2]) | ((unsigned)f2bf(v[3]) << 16);
    st.z = (unsigned)f2bf(v[4]) | ((unsigned)f2bf(v[5]) << 16);
    st.w = (unsigned)f2bf(v[6]) | ((unsigned)f2bf(v[7]) << 16);
    *reinterpret_cast<uint4*>(&dst[(size_t)(n0 + ng + nn) * K + kk]) = st;
  }
}

// ---------------- router: logits, top-4, per-token sel/weights. NO atomics. ----------------
__global__ void router_kernel(const float* __restrict__ x, const float* __restrict__ wgT,
                              float* __restrict__ rl, unsigned* __restrict__ selmask,
                              float* __restrict__ wsel) {
  int lane = threadIdx.x & 63, wv = threadIdx.x >> 6;
  int t = blockIdx.x * 4 + wv;          // one wave per token
  const float* xr = x + (size_t)t * HH;
  float xv[16];
#pragma unroll
  for (int i = 0; i < 16; ++i) xv[i] = xr[lane + 64 * i];
  float lg[16];
#pragma unroll
  for (int e = 0; e < 16; ++e) {
    const float* wr = wgT + (size_t)e * HH;
    float p = 0.f;
#pragma unroll
    for (int i = 0; i < 16; ++i) p += xv[i] * wr[lane + 64 * i];
#pragma unroll
    for (int s = 32; s > 0; s >>= 1) p += __shfl_xor(p, s, 64);
    lg[e] = p;   // all lanes hold the full logit after butterfly
  }
  if (lane < 16) rl[(size_t)t * 16 + lane] = lg[lane];
  // top-4 (stable: earlier index wins ties, matches lax.top_k)
  unsigned mask = 0;
  int sel[4]; float bl[4];
#pragma unroll
  for (int k = 0; k < 4; ++k) {
    float best = -3.4e38f; int bi = 0;
#pragma unroll
    for (int e = 0; e < 16; ++e) {
      bool ok = !((mask >> e) & 1u) && (lg[e] > best);
      best = ok ? lg[e] : best;
      bi = ok ? e : bi;
    }
    mask |= 1u << bi;
    sel[k] = bi; bl[k] = best;
  }
  // normalized top-k softmax: full denominator cancels
  float mx = bl[0];
  float wk[4]; float s = 0.f;
#pragma unroll
  for (int k = 0; k < 4; ++k) { wk[k] = expf(bl[k] - mx); s += wk[k]; }
  float inv = 1.f / s;
  if (lane == 0) {
    selmask[t] = (unsigned)sel[0] | ((unsigned)sel[1] << 4) |
                 ((unsigned)sel[2] << 8) | ((unsigned)sel[3] << 12);
    float4 w4 = make_float4(wk[0] * inv, wk[1] * inv, wk[2] * inv, wk[3] * inv);
    reinterpret_cast<float4*>(wsel)[t] = w4;
  }
}

// ---------------- build per-expert lists: 1 block, 16 waves, ballot-compaction ----------------
// R5: two-pass so pass 2 can also emit rowof[t][k] = global hidden-row of (t, k-th pick),
// which lets the down-GEMM store densely and a combine kernel gather (no atomics).
__global__ void build_lists_kernel(const unsigned* __restrict__ selmask,
                                   const float* __restrict__ wsel,
                                   int* __restrict__ counts, int* __restrict__ offsets,
                                   int* __restrict__ tlist, float* __restrict__ wlist,
                                   int* __restrict__ rowof) {
  __shared__ int scnt[16];
  __shared__ int soff[16];
  int lane = threadIdx.x & 63, e = threadIdx.x >> 6;   // wave e handles expert e
  // pass 1: count only
  int base = 0;
  for (int t0 = 0; t0 < TT; t0 += 64) {
    unsigned m = selmask[t0 + lane];
    bool hit = false;
#pragma unroll
    for (int j = 0; j < 4; ++j)
      hit |= (((m >> (4 * j)) & 15u) == (unsigned)e);
    base += (int)__popcll(__ballot(hit));
  }
  if (lane == 0) scnt[e] = base;
  __syncthreads();
  if (threadIdx.x == 0) {
    int s = 0;
    for (int i = 0; i < 16; ++i) { counts[i] = scnt[i]; offsets[i] = s; soff[i] = s; s += scnt[i]; }
    offsets[16] = s;
  }
  __syncthreads();
  // pass 2: write compacted lists + inverse map
  int hb = soff[e];
  base = 0;
  for (int t0 = 0; t0 < TT; t0 += 64) {
    int t = t0 + lane;
    unsigned m = selmask[t];
    int k = -1;
#pragma unroll
    for (int j = 0; j < 4; ++j)
      if (((m >> (4 * j)) & 15u) == (unsigned)e) k = j;
    unsigned long long bal = __ballot(k >= 0);
    int pos = base + (int)__popcll(bal & ((1ull << lane) - 1ull));
    if (k >= 0) {
      tlist[e * TT + pos] = t;
      wlist[e * TT + pos] = wsel[t * 4 + k];
      rowof[t * 4 + k] = hb + pos;
    }
    base += (int)__popcll(bal);
  }
}

// ---------------- gate+up fused GEMM -> hidden (bf16, pre-scaled by routing weight) ----------------
// R4: tile 128(M)x64(N), BK=64, swizzled LDS. 4 waves 2x2: wave = 64 rows x 32 cols.
__global__ __launch_bounds__(256, 2) void gateup_kernel(
    const u16* __restrict__ xb, const u16* __restrict__ wgt, const u16* __restrict__ wut,
    const int* __restrict__ counts, const int* __restrict__ offsets,
    const int* __restrict__ tlist, const float* __restrict__ wlist,
    u16* __restrict__ hidden) {
  int e = blockIdx.z, mt = blockIdx.y, nt = blockIdx.x;   // nt 0..7 (64 cols each)
  int cnt = counts[e];
  if (mt * 128 >= cnt) return;
  __shared__ u16 As[128 * 64];   // [m][k] swizzled
  __shared__ u16 Bg[64 * 64];    // [n][k] swizzled
  __shared__ u16 Bu[64 * 64];
  int tid = threadIdx.x, lane = tid & 63, wv = tid >> 6;
  int wm = wv >> 1, wn = wv & 1;
  int srow = lane >> 3;                     // staging row within 8-row chunk
  int scol = (((lane & 7) ^ srow)) * 8;     // swizzled global k-offset (u16)
  const u16* wgE = wgt + (size_t)e * II * HH;
  const u16* wuE = wut + (size_t)e * II * HH;
  const u16* gp[8];
#pragma unroll
  for (int c = 0; c < 8; ++c) {
    int chunk = c * 4 + wv;
    const u16* p;
    if (chunk < 16) {
      int mi = mt * 128 + chunk * 8 + srow; if (mi >= cnt) mi = cnt - 1;
      int tok = tlist[e * TT + mi];
      p = xb + (size_t)tok * HH + scol;
    } else if (chunk < 24) {
      int n = nt * 64 + (chunk - 16) * 8 + srow;
      p = wgE + (size_t)n * HH + scol;
    } else {
      int n = nt * 64 + (chunk - 24) * 8 + srow;
      p = wuE + (size_t)n * HH + scol;
    }
    gp[c] = p;
  }
  f32x4 accG[4][2] = {}; f32x4 accU[4][2] = {};
  int quad = lane >> 4, colc = lane & 15;
  for (int k0 = 0; k0 < HH; k0 += 64) {
#pragma unroll
    for (int c = 0; c < 8; ++c) {
      int chunk = c * 4 + wv;
      u16* dst = (chunk < 16) ? &As[chunk * 512]
               : (chunk < 24) ? &Bg[(chunk - 16) * 512]
                              : &Bu[(chunk - 24) * 512];
      gl2lds16(gp[c] + k0, dst);
    }
    __syncthreads();
#pragma unroll
    for (int kk = 0; kk < 64; kk += 32) {
      int gl = (kk >> 3) + quad;            // logical k-group
      s16x8 a[4], bg[2], bu[2];
#pragma unroll
      for (int f = 0; f < 4; ++f) {
        int m = wm * 64 + f * 16 + colc;
        a[f] = *reinterpret_cast<const s16x8*>(&As[m * 64 + ((gl ^ (m & 7)) << 3)]);
      }
#pragma unroll
      for (int f = 0; f < 2; ++f) {
        int n = wn * 32 + f * 16 + colc;
        bg[f] = *reinterpret_cast<const s16x8*>(&Bg[n * 64 + ((gl ^ (n & 7)) << 3)]);
        bu[f] = *reinterpret_cast<const s16x8*>(&Bu[n * 64 + ((gl ^ (n & 7)) << 3)]);
      }
#pragma unroll
      for (int fm = 0; fm < 4; ++fm)
#pragma unroll
        for (int fn = 0; fn < 2; ++fn) {
          accG[fm][fn] = __builtin_amdgcn_mfma_f32_16x16x32_bf16(a[fm], bg[fn], accG[fm][fn], 0, 0, 0);
          accU[fm][fn] = __builtin_amdgcn_mfma_f32_16x16x32_bf16(a[fm], bu[fn], accU[fm][fn], 0, 0, 0);
        }
    }
    __syncthreads();
  }
  // epilogue: hidden = w_route * silu(g) * u   (C/D: col=lane&15, row=quad*4+reg)
  int hb = offsets[e];
#pragma unroll
  for (int fm = 0; fm < 4; ++fm) {
#pragma unroll
    for (int r = 0; r < 4; ++r) {
      int mi = mt * 128 + wm * 64 + fm * 16 + quad * 4 + r;
      if (mi < cnt) {
        float wr = wlist[e * TT + mi];
        u16* hrow = hidden + (size_t)(hb + mi) * II + nt * 64 + wn * 32;
#pragma unroll
        for (int fn = 0; fn < 2; ++fn) {
          float g = accG[fm][fn][r], u = accU[fm][fn][r];
          float hval = wr * u * g / (1.f + expf(-g));
          hrow[fn * 16 + colc] = f2bf(hval);
        }
      }
    }
  }
}

// ---------------- down GEMM: hidden @ wd^T -> dense bf16 rows in dtmp (no atomics) ----------------
__global__ __launch_bounds__(256, 2) void down_kernel(
    const u16* __restrict__ hidden, const u16* __restrict__ wdt,
    const int* __restrict__ counts, const int* __restrict__ offsets,
    u16* __restrict__ dtmp) {
  int e = blockIdx.z, mt = blockIdx.y, nt = blockIdx.x;
  int cnt = counts[e];
  if (mt * 128 >= cnt) return;
  int hb = offsets[e];
  __shared__ u16 As[128 * 64];
  __shared__ u16 Bs[128 * 64];
  int tid = threadIdx.x, lane = tid & 63, wv = tid >> 6;
  int wm = wv >> 1, wn = wv & 1;
  int srow = lane >> 3;
  int scol = (((lane & 7) ^ srow)) * 8;     // swizzled global k-offset
  const u16* wdE = wdt + (size_t)e * HH * II;
  const u16* gA[4]; const u16* gB[4];
#pragma unroll
  for (int c = 0; c < 4; ++c) {
    int chunk = c * 4 + wv;
    int row = hb + mt * 128 + chunk * 8 + srow;
    if (row > 8191) row = 8191;   // clamp pad rows into the hidden buffer
    gA[c] = hidden + (size_t)row * II + scol;
    int n = nt * 128 + chunk * 8 + srow;
    gB[c] = wdE + (size_t)n * II + scol;
  }
  f32x4 acc[4][4] = {};
  int quad = lane >> 4, colc = lane & 15;
  for (int k0 = 0; k0 < II; k0 += 64) {
#pragma unroll
    for (int c = 0; c < 4; ++c) {
      int chunk = c * 4 + wv;
      gl2lds16(gA[c] + k0, &As[chunk * 512]);
      gl2lds16(gB[c] + k0, &Bs[chunk * 512]);
    }
    __syncthreads();
#pragma unroll
    for (int kk = 0; kk < 64; kk += 32) {
      int gl = (kk >> 3) + quad;
      s16x8 a[4], b[4];
#pragma unroll
      for (int f = 0; f < 4; ++f) {
        int m = wm * 64 + f * 16 + colc;
        int n = wn * 64 + f * 16 + colc;
        a[f] = *reinterpret_cast<const s16x8*>(&As[m * 64 + ((gl ^ (m & 7)) << 3)]);
        b[f] = *reinterpret_cast<const s16x8*>(&Bs[n * 64 + ((gl ^ (n & 7)) << 3)]);
      }
#pragma unroll
      for (int fm = 0; fm < 4; ++fm)
#pragma unroll
        for (int fn = 0; fn < 4; ++fn)
          acc[fm][fn] = __builtin_amdgcn_mfma_f32_16x16x32_bf16(a[fm], b[fn], acc[fm][fn], 0, 0, 0);
    }
    __syncthreads();
  }
#pragma unroll
  for (int fm = 0; fm < 4; ++fm) {
#pragma unroll
    for (int r = 0; r < 4; ++r) {
      int mi = mt * 128 + wm * 64 + fm * 16 + quad * 4 + r;
      if (mi < cnt) {
        u16* drow = dtmp + (size_t)(hb + mi) * HH + nt * 128 + wn * 64;
#pragma unroll
        for (int fn = 0; fn < 4; ++fn)
          drow[fn * 16 + colc] = f2bf(acc[fm][fn][r]);
      }
    }
  }
}

// ---------------- combine: out[t] = sum of 4 expert rows (routing weight already applied) ----------------
__global__ void combine_kernel(const u16* __restrict__ dtmp, const int* __restrict__ rowof,
                               float* __restrict__ out) {
  int t = blockIdx.x, tid = threadIdx.x;
  int4 rw = reinterpret_cast<const int4*>(rowof)[t];
  int h = tid * 4;
  float s0 = 0.f, s1 = 0.f, s2 = 0.f, s3 = 0.f;
  int rows[4] = {rw.x, rw.y, rw.z, rw.w};
#pragma unroll
  for (int k = 0; k < 4; ++k) {
    ushort4 v = *reinterpret_cast<const ushort4*>(&dtmp[(size_t)rows[k] * HH + h]);
    s0 += bf2f(v.x); s1 += bf2f(v.y); s2 += bf2f(v.z); s3 += bf2f(v.w);
  }
  *reinterpret_cast<float4*>(&out[(size_t)t * HH + h]) = make_float4(s0, s1, s2, s3);
}

extern "C" void kernel_launch(void* const* d_in, const int* in_sizes, int n_in,
                              void* d_out, int out_size, void* d_ws, size_t ws_size,
                              hipStream_t stream) {
  const float* x   = (const float*)d_in[0];   // [1,2048,1024]
  const float* wg  = (const float*)d_in[1];   // [1024,16]
  const float* wgp = (const float*)d_in[2];   // [16,1024,512]
  const float* wup = (const float*)d_in[3];   // [16,1024,512]
  const float* wdp = (const float*)d_in[4];   // [16,512,1024]
  float* out = (float*)d_out;                 // [2048*1024] then router_logits [2048*16]
  float* rl  = out + (size_t)TT * HH;

  char* w = (char*)d_ws;
  int*      counts  = (int*)(w + 0);                  // 16 ints
  int*      offsets = (int*)(w + 64);                 // 17 ints
  unsigned* selmask = (unsigned*)(w + 1024);          // [T] packed 4x4-bit expert ids
  float*    wsel    = (float*)(w + 16384);            // [T][4] normalized weights (32 KB)
  int*      rowof   = (int*)(w + 49152);              // [T][4] global hidden-row ids (32 KB)
  int*      tlist   = (int*)(w + 81920);              // [E][T] token ids (128 KB)
  float*    wlist   = (float*)(w + 210944);           // [E][T] routing weights (128 KB)
  float*    wgT     = (float*)(w + 339968);           // [E][H] fp32 transposed router weights
  u16*      xb      = (u16*)(w + 405504);             // [T][H] bf16 (4 MB)
  u16*      wgt     = xb  + (size_t)TT * HH;          // [E][I][H] bf16 (transposed, 16 MB)
  u16*      wut     = wgt + (size_t)EE * II * HH;     // 16 MB
  u16*      wdt     = wut + (size_t)EE * II * HH;     // [E][H][I] bf16 (transposed, 16 MB)
  u16*      hidden  = wdt + (size_t)EE * HH * II;     // [8192][I] bf16 (8 MB)
  u16*      dtmp    = wgt;   // [8192][H] bf16 (16 MB) — safely aliases wgt: gateup
                             // (last reader of wgt) completes before down runs.

  hipLaunchKernelGGL(cast_x_kernel, dim3(TT * HH / 1024 + 64), dim3(256), 0, stream,
                     x, xb, wg, wgT);
  hipLaunchKernelGGL(wtrans_kernel, dim3(3072), dim3(256), 0, stream,
                     wgp, wup, wdp, wgt, wut, wdt);
  hipLaunchKernelGGL(router_kernel, dim3(TT / 4), dim3(256), 0, stream,
                     x, wgT, rl, selmask, wsel);
  hipLaunchKernelGGL(build_lists_kernel, dim3(1), dim3(1024), 0, stream,
                     selmask, wsel, counts, offsets, tlist, wlist, rowof);
  hipLaunchKernelGGL(gateup_kernel, dim3(8, 16, 16), dim3(256), 0, stream,
                     xb, wgt, wut, counts, offsets, tlist, wlist, hidden);
  hipLaunchKernelGGL(down_kernel, dim3(8, 16, 16), dim3(256), 0, stream,
                     hidden, wdt, counts, offsets, dtmp);
  hipLaunchKernelGGL(combine_kernel, dim3(TT), dim3(256), 0, stream,
                     dtmp, rowof, out);
}

// Round 7
// 228.997 us; speedup vs baseline: 1.5089x; 1.0664x over previous
//
#include <hip/hip_runtime.h>
#include <math.h>

// Qwen3 MoE sparse block, MI355X/gfx950.
// Sizes fixed by the reference: T=2048 tokens, H=1024, E=16, I=512, top-4.
constexpr int TT = 2048;   // tokens
constexpr int HH = 1024;   // hidden
constexpr int EE = 16;     // experts
constexpr int II = 512;    // intermediate

typedef unsigned short u16;
typedef short s16x8 __attribute__((ext_vector_type(8)));   // 8 bf16 for MFMA A/B
typedef float f32x4 __attribute__((ext_vector_type(4)));   // MFMA C/D

__device__ __forceinline__ u16 f2bf(float f) {
  unsigned u = __float_as_uint(f);
  u = (u + 0x7fffu + ((u >> 16) & 1u)) >> 16;   // round-to-nearest-even
  return (u16)u;
}
__device__ __forceinline__ float bf2f(u16 b) {
  return __uint_as_float(((unsigned)b) << 16);
}

// async global->LDS, 16B per lane; lds base must be wave-uniform (HW adds lane*16)
__device__ __forceinline__ void gl2lds16(const void* g, void* l) {
  __builtin_amdgcn_global_load_lds(
      (const __attribute__((address_space(1))) unsigned*)g,
      (__attribute__((address_space(3))) unsigned*)l, 16, 0, 0);
}

// ---------------- prep mega-kernel: weight transpose v4 + cast x + wgT ----------------
// wtrans v4 (R6): tile 64n x 32k, lane owns 1n x 8k. Store instr = 16 rows x 64B
// contiguous granules (R5 v3 scattered 64x16B granules/instr -> ~3.1M L2 requests was
// the 2 TB/s wall). Load instr j = 4 k-rows x 64B granules. No LDS, no barriers.
__global__ __launch_bounds__(256) void prep_kernel(
    const float* __restrict__ wgp, const float* __restrict__ wup,
    const float* __restrict__ wdp, u16* __restrict__ wgt,
    u16* __restrict__ wut, u16* __restrict__ wdt,
    const float* __restrict__ x, u16* __restrict__ xb,
    const float* __restrict__ wg, float* __restrict__ wgT) {
  int bid = blockIdx.x;
  int tid = threadIdx.x;
  if (bid < 12288) {
    // ---- weight transpose: 48 regions x 256 blocks ----
    int z = bid >> 8, lb = bid & 255;
    int e = z & 15, t = z >> 4;
    const float* src; u16* dst; int K, N;
    if (t == 0)      { src = wgp + (size_t)e * HH * II; dst = wgt + (size_t)e * II * HH; K = HH; N = II; }
    else if (t == 1) { src = wup + (size_t)e * HH * II; dst = wut + (size_t)e * II * HH; K = HH; N = II; }
    else             { src = wdp + (size_t)e * II * HH; dst = wdt + (size_t)e * HH * II; K = II; N = HH; }
    int nTiles = N >> 6;                 // 64-wide n tiles
    int n0 = (lb % nTiles) * 64;
    int k0 = (lb / nTiles) * 32;         // 32-deep k tiles
    int l = tid & 63, w = tid >> 6;
    int n  = n0 + w * 16 + (l >> 2);     // 1 n per thread
    int kc = l & 3;                      // k-chunk: 8 consecutive k
    float v[8];
#pragma unroll
    for (int j = 0; j < 8; ++j)
      v[j] = src[(size_t)(k0 + kc * 8 + j) * N + n];
    uint4 st;
    st.x = (unsigned)f2bf(v[0]) | ((unsigned)f2bf(v[1]) << 16);
    st.y = (unsigned)f2bf(v[2]) | ((unsigned)f2bf(v[3]) << 16);
    st.z = (unsigned)f2bf(v[4]) | ((unsigned)f2bf(v[5]) << 16);
    st.w = (unsigned)f2bf(v[6]) | ((unsigned)f2bf(v[7]) << 16);
    *reinterpret_cast<uint4*>(&dst[(size_t)n * K + k0 + kc * 8]) = st;
  } else if (bid < 12288 + 2048) {
    // ---- cast x fp32 -> bf16 ----
    int i = (bid - 12288) * 256 + tid;
    float4 v = reinterpret_cast<const float4*>(x)[i];
    ushort4 o;
    o.x = f2bf(v.x); o.y = f2bf(v.y); o.z = f2bf(v.z); o.w = f2bf(v.w);
    reinterpret_cast<ushort4*>(xb)[i] = o;
  } else {
    // ---- transpose wg [H][E] -> wgT [E][H] fp32 (64 blocks) ----
    int i = (bid - 12288 - 2048) * 256 + tid;
    int h = i >> 4, e = i & 15;
    wgT[e * HH + h] = wg[i];
  }
}

// ---------------- router: logits, top-4, per-token sel/weights. NO atomics. ----------------
__global__ void router_kernel(const float* __restrict__ x, const float* __restrict__ wgT,
                              float* __restrict__ rl, unsigned* __restrict__ selmask,
                              float* __restrict__ wsel) {
  int lane = threadIdx.x & 63, wv = threadIdx.x >> 6;
  int t = blockIdx.x * 4 + wv;          // one wave per token
  const float* xr = x + (size_t)t * HH;
  float xv[16];
#pragma unroll
  for (int i = 0; i < 16; ++i) xv[i] = xr[lane + 64 * i];
  float lg[16];
#pragma unroll
  for (int e = 0; e < 16; ++e) {
    const float* wr = wgT + (size_t)e * HH;
    float p = 0.f;
#pragma unroll
    for (int i = 0; i < 16; ++i) p += xv[i] * wr[lane + 64 * i];
#pragma unroll
    for (int s = 32; s > 0; s >>= 1) p += __shfl_xor(p, s, 64);
    lg[e] = p;   // all lanes hold the full logit after butterfly
  }
  if (lane < 16) rl[(size_t)t * 16 + lane] = lg[lane];
  // top-4 (stable: earlier index wins ties, matches lax.top_k)
  unsigned mask = 0;
  int sel[4]; float bl[4];
#pragma unroll
  for (int k = 0; k < 4; ++k) {
    float best = -3.4e38f; int bi = 0;
#pragma unroll
    for (int e = 0; e < 16; ++e) {
      bool ok = !((mask >> e) & 1u) && (lg[e] > best);
      best = ok ? lg[e] : best;
      bi = ok ? e : bi;
    }
    mask |= 1u << bi;
    sel[k] = bi; bl[k] = best;
  }
  // normalized top-k softmax: full denominator cancels
  float mx = bl[0];
  float wk[4]; float s = 0.f;
#pragma unroll
  for (int k = 0; k < 4; ++k) { wk[k] = expf(bl[k] - mx); s += wk[k]; }
  float inv = 1.f / s;
  if (lane == 0) {
    selmask[t] = (unsigned)sel[0] | ((unsigned)sel[1] << 4) |
                 ((unsigned)sel[2] << 8) | ((unsigned)sel[3] << 12);
    float4 w4 = make_float4(wk[0] * inv, wk[1] * inv, wk[2] * inv, wk[3] * inv);
    reinterpret_cast<float4*>(wsel)[t] = w4;
  }
}

// ---------------- build per-expert lists: 1 block, 16 waves, ballot-compaction ----------------
// Two-pass; also emits rowof[t][k] = global hidden-row of (t, k-th pick) for the
// atomic-free down/combine path.
__global__ void build_lists_kernel(const unsigned* __restrict__ selmask,
                                   const float* __restrict__ wsel,
                                   int* __restrict__ counts, int* __restrict__ offsets,
                                   int* __restrict__ tlist, float* __restrict__ wlist,
                                   int* __restrict__ rowof) {
  __shared__ int scnt[16];
  __shared__ int soff[16];
  int lane = threadIdx.x & 63, e = threadIdx.x >> 6;   // wave e handles expert e
  // pass 1: count only
  int base = 0;
  for (int t0 = 0; t0 < TT; t0 += 64) {
    unsigned m = selmask[t0 + lane];
    bool hit = false;
#pragma unroll
    for (int j = 0; j < 4; ++j)
      hit |= (((m >> (4 * j)) & 15u) == (unsigned)e);
    base += (int)__popcll(__ballot(hit));
  }
  if (lane == 0) scnt[e] = base;
  __syncthreads();
  if (threadIdx.x == 0) {
    int s = 0;
    for (int i = 0; i < 16; ++i) { counts[i] = scnt[i]; offsets[i] = s; soff[i] = s; s += scnt[i]; }
    offsets[16] = s;
  }
  __syncthreads();
  // pass 2: write compacted lists + inverse map
  int hb = soff[e];
  base = 0;
  for (int t0 = 0; t0 < TT; t0 += 64) {
    int t = t0 + lane;
    unsigned m = selmask[t];
    int k = -1;
#pragma unroll
    for (int j = 0; j < 4; ++j)
      if (((m >> (4 * j)) & 15u) == (unsigned)e) k = j;
    unsigned long long bal = __ballot(k >= 0);
    int pos = base + (int)__popcll(bal & ((1ull << lane) - 1ull));
    if (k >= 0) {
      tlist[e * TT + pos] = t;
      wlist[e * TT + pos] = wsel[t * 4 + k];
      rowof[t * 4 + k] = hb + pos;
    }
    base += (int)__popcll(bal);
  }
}

// ---------------- gate+up fused GEMM -> hidden (bf16, pre-scaled by routing weight) ----------------
// R4: tile 128(M)x64(N), BK=64, swizzled LDS. 4 waves 2x2: wave = 64 rows x 32 cols.
__global__ __launch_bounds__(256, 2) void gateup_kernel(
    const u16* __restrict__ xb, const u16* __restrict__ wgt, const u16* __restrict__ wut,
    const int* __restrict__ counts, const int* __restrict__ offsets,
    const int* __restrict__ tlist, const float* __restrict__ wlist,
    u16* __restrict__ hidden) {
  int e = blockIdx.z, mt = blockIdx.y, nt = blockIdx.x;   // nt 0..7 (64 cols each)
  int cnt = counts[e];
  if (mt * 128 >= cnt) return;
  __shared__ u16 As[128 * 64];   // [m][k] swizzled
  __shared__ u16 Bg[64 * 64];    // [n][k] swizzled
  __shared__ u16 Bu[64 * 64];
  int tid = threadIdx.x, lane = tid & 63, wv = tid >> 6;
  int wm = wv >> 1, wn = wv & 1;
  int srow = lane >> 3;                     // staging row within 8-row chunk
  int scol = (((lane & 7) ^ srow)) * 8;     // swizzled global k-offset (u16)
  const u16* wgE = wgt + (size_t)e * II * HH;
  const u16* wuE = wut + (size_t)e * II * HH;
  const u16* gp[8];
#pragma unroll
  for (int c = 0; c < 8; ++c) {
    int chunk = c * 4 + wv;
    const u16* p;
    if (chunk < 16) {
      int mi = mt * 128 + chunk * 8 + srow; if (mi >= cnt) mi = cnt - 1;
      int tok = tlist[e * TT + mi];
      p = xb + (size_t)tok * HH + scol;
    } else if (chunk < 24) {
      int n = nt * 64 + (chunk - 16) * 8 + srow;
      p = wgE + (size_t)n * HH + scol;
    } else {
      int n = nt * 64 + (chunk - 24) * 8 + srow;
      p = wuE + (size_t)n * HH + scol;
    }
    gp[c] = p;
  }
  f32x4 accG[4][2] = {}; f32x4 accU[4][2] = {};
  int quad = lane >> 4, colc = lane & 15;
  for (int k0 = 0; k0 < HH; k0 += 64) {
#pragma unroll
    for (int c = 0; c < 8; ++c) {
      int chunk = c * 4 + wv;
      u16* dst = (chunk < 16) ? &As[chunk * 512]
               : (chunk < 24) ? &Bg[(chunk - 16) * 512]
                              : &Bu[(chunk - 24) * 512];
      gl2lds16(gp[c] + k0, dst);
    }
    __syncthreads();
#pragma unroll
    for (int kk = 0; kk < 64; kk += 32) {
      int gl = (kk >> 3) + quad;            // logical k-group
      s16x8 a[4], bg[2], bu[2];
#pragma unroll
      for (int f = 0; f < 4; ++f) {
        int m = wm * 64 + f * 16 + colc;
        a[f] = *reinterpret_cast<const s16x8*>(&As[m * 64 + ((gl ^ (m & 7)) << 3)]);
      }
#pragma unroll
      for (int f = 0; f < 2; ++f) {
        int n = wn * 32 + f * 16 + colc;
        bg[f] = *reinterpret_cast<const s16x8*>(&Bg[n * 64 + ((gl ^ (n & 7)) << 3)]);
        bu[f] = *reinterpret_cast<const s16x8*>(&Bu[n * 64 + ((gl ^ (n & 7)) << 3)]);
      }
#pragma unroll
      for (int fm = 0; fm < 4; ++fm)
#pragma unroll
        for (int fn = 0; fn < 2; ++fn) {
          accG[fm][fn] = __builtin_amdgcn_mfma_f32_16x16x32_bf16(a[fm], bg[fn], accG[fm][fn], 0, 0, 0);
          accU[fm][fn] = __builtin_amdgcn_mfma_f32_16x16x32_bf16(a[fm], bu[fn], accU[fm][fn], 0, 0, 0);
        }
    }
    __syncthreads();
  }
  // epilogue: hidden = w_route * silu(g) * u   (C/D: col=lane&15, row=quad*4+reg)
  int hb = offsets[e];
#pragma unroll
  for (int fm = 0; fm < 4; ++fm) {
#pragma unroll
    for (int r = 0; r < 4; ++r) {
      int mi = mt * 128 + wm * 64 + fm * 16 + quad * 4 + r;
      if (mi < cnt) {
        float wr = wlist[e * TT + mi];
        u16* hrow = hidden + (size_t)(hb + mi) * II + nt * 64 + wn * 32;
#pragma unroll
        for (int fn = 0; fn < 2; ++fn) {
          float g = accG[fm][fn][r], u = accU[fm][fn][r];
          float hval = wr * u * g / (1.f + expf(-g));
          hrow[fn * 16 + colc] = f2bf(hval);
        }
      }
    }
  }
}

// ---------------- down GEMM: hidden @ wd^T -> dense bf16 rows in dtmp (no atomics) ----------------
__global__ __launch_bounds__(256, 2) void down_kernel(
    const u16* __restrict__ hidden, const u16* __restrict__ wdt,
    const int* __restrict__ counts, const int* __restrict__ offsets,
    u16* __restrict__ dtmp) {
  int e = blockIdx.z, mt = blockIdx.y, nt = blockIdx.x;
  int cnt = counts[e];
  if (mt * 128 >= cnt) return;
  int hb = offsets[e];
  __shared__ u16 As[128 * 64];
  __shared__ u16 Bs[128 * 64];
  int tid = threadIdx.x, lane = tid & 63, wv = tid >> 6;
  int wm = wv >> 1, wn = wv & 1;
  int srow = lane >> 3;
  int scol = (((lane & 7) ^ srow)) * 8;     // swizzled global k-offset
  const u16* wdE = wdt + (size_t)e * HH * II;
  const u16* gA[4]; const u16* gB[4];
#pragma unroll
  for (int c = 0; c < 4; ++c) {
    int chunk = c * 4 + wv;
    int row = hb + mt * 128 + chunk * 8 + srow;
    if (row > 8191) row = 8191;   // clamp pad rows into the hidden buffer
    gA[c] = hidden + (size_t)row * II + scol;
    int n = nt * 128 + chunk * 8 + srow;
    gB[c] = wdE + (size_t)n * II + scol;
  }
  f32x4 acc[4][4] = {};
  int quad = lane >> 4, colc = lane & 15;
  for (int k0 = 0; k0 < II; k0 += 64) {
#pragma unroll
    for (int c = 0; c < 4; ++c) {
      int chunk = c * 4 + wv;
      gl2lds16(gA[c] + k0, &As[chunk * 512]);
      gl2lds16(gB[c] + k0, &Bs[chunk * 512]);
    }
    __syncthreads();
#pragma unroll
    for (int kk = 0; kk < 64; kk += 32) {
      int gl = (kk >> 3) + quad;
      s16x8 a[4], b[4];
#pragma unroll
      for (int f = 0; f < 4; ++f) {
        int m = wm * 64 + f * 16 + colc;
        int n = wn * 64 + f * 16 + colc;
        a[f] = *reinterpret_cast<const s16x8*>(&As[m * 64 + ((gl ^ (m & 7)) << 3)]);
        b[f] = *reinterpret_cast<const s16x8*>(&Bs[n * 64 + ((gl ^ (n & 7)) << 3)]);
      }
#pragma unroll
      for (int fm = 0; fm < 4; ++fm)
#pragma unroll
        for (int fn = 0; fn < 4; ++fn)
          acc[fm][fn] = __builtin_amdgcn_mfma_f32_16x16x32_bf16(a[fm], b[fn], acc[fm][fn], 0, 0, 0);
    }
    __syncthreads();
  }
#pragma unroll
  for (int fm = 0; fm < 4; ++fm) {
#pragma unroll
    for (int r = 0; r < 4; ++r) {
      int mi = mt * 128 + wm * 64 + fm * 16 + quad * 4 + r;
      if (mi < cnt) {
        u16* drow = dtmp + (size_t)(hb + mi) * HH + nt * 128 + wn * 64;
#pragma unroll
        for (int fn = 0; fn < 4; ++fn)
          drow[fn * 16 + colc] = f2bf(acc[fm][fn][r]);
      }
    }
  }
}

// ---------------- combine: out[t] = sum of 4 expert rows (routing weight already applied) ----------------
__global__ void combine_kernel(const u16* __restrict__ dtmp, const int* __restrict__ rowof,
                               float* __restrict__ out) {
  int t = blockIdx.x, tid = threadIdx.x;
  int4 rw = reinterpret_cast<const int4*>(rowof)[t];
  int h = tid * 4;
  float s0 = 0.f, s1 = 0.f, s2 = 0.f, s3 = 0.f;
  int rows[4] = {rw.x, rw.y, rw.z, rw.w};
#pragma unroll
  for (int k = 0; k < 4; ++k) {
    ushort4 v = *reinterpret_cast<const ushort4*>(&dtmp[(size_t)rows[k] * HH + h]);
    s0 += bf2f(v.x); s1 += bf2f(v.y); s2 += bf2f(v.z); s3 += bf2f(v.w);
  }
  *reinterpret_cast<float4*>(&out[(size_t)t * HH + h]) = make_float4(s0, s1, s2, s3);
}

extern "C" void kernel_launch(void* const* d_in, const int* in_sizes, int n_in,
                              void* d_out, int out_size, void* d_ws, size_t ws_size,
                              hipStream_t stream) {
  const float* x   = (const float*)d_in[0];   // [1,2048,1024]
  const float* wg  = (const float*)d_in[1];   // [1024,16]
  const float* wgp = (const float*)d_in[2];   // [16,1024,512]
  const float* wup = (const float*)d_in[3];   // [16,1024,512]
  const float* wdp = (const float*)d_in[4];   // [16,512,1024]
  float* out = (float*)d_out;                 // [2048*1024] then router_logits [2048*16]
  float* rl  = out + (size_t)TT * HH;

  char* w = (char*)d_ws;
  int*      counts  = (int*)(w + 0);                  // 16 ints
  int*      offsets = (int*)(w + 64);                 // 17 ints
  unsigned* selmask = (unsigned*)(w + 1024);          // [T] packed 4x4-bit expert ids
  float*    wsel    = (float*)(w + 16384);            // [T][4] normalized weights (32 KB)
  int*      rowof   = (int*)(w + 49152);              // [T][4] global hidden-row ids (32 KB)
  int*      tlist   = (int*)(w + 81920);              // [E][T] token ids (128 KB)
  float*    wlist   = (float*)(w + 210944);           // [E][T] routing weights (128 KB)
  float*    wgT     = (float*)(w + 339968);           // [E][H] fp32 transposed router weights
  u16*      xb      = (u16*)(w + 405504);             // [T][H] bf16 (4 MB)
  u16*      wgt     = xb  + (size_t)TT * HH;          // [E][I][H] bf16 (transposed, 16 MB)
  u16*      wut     = wgt + (size_t)EE * II * HH;     // 16 MB
  u16*      wdt     = wut + (size_t)EE * II * HH;     // [E][H][I] bf16 (transposed, 16 MB)
  u16*      hidden  = wdt + (size_t)EE * HH * II;     // [8192][I] bf16 (8 MB)
  u16*      dtmp    = wgt;   // [8192][H] bf16 (16 MB) — safely aliases wgt: gateup
                             // (last reader of wgt) completes before down runs.

  hipLaunchKernelGGL(prep_kernel, dim3(12288 + 2048 + 64), dim3(256), 0, stream,
                     wgp, wup, wdp, wgt, wut, wdt, x, xb, wg, wgT);
  hipLaunchKernelGGL(router_kernel, dim3(TT / 4), dim3(256), 0, stream,
                     x, wgT, rl, selmask, wsel);
  hipLaunchKernelGGL(build_lists_kernel, dim3(1), dim3(1024), 0, stream,
                     selmask, wsel, counts, offsets, tlist, wlist, rowof);
  hipLaunchKernelGGL(gateup_kernel, dim3(8, 16, 16), dim3(256), 0, stream,
                     xb, wgt, wut, counts, offsets, tlist, wlist, hidden);
  hipLaunchKernelGGL(down_kernel, dim3(8, 16, 16), dim3(256), 0, stream,
                     hidden, wdt, counts, offsets, dtmp);
  hipLaunchKernelGGL(combine_kernel, dim3(TT), dim3(256), 0, stream,
                     dtmp, rowof, out);
}